// Round 1
// baseline (2354.615 us; speedup 1.0000x reference)
//
#include <hip/hip_runtime.h>
#include <hip/hip_bf16.h>

#define NB 32
#define NS 1024
#define NH 1024

typedef short s16x4 __attribute__((ext_vector_type(4)));
typedef short s16x8 __attribute__((ext_vector_type(8)));
typedef float f32x4 __attribute__((ext_vector_type(4)));

typedef __attribute__((address_space(3))) void lds_void;
typedef const __attribute__((address_space(1))) void gmem_void;

__device__ __forceinline__ short f2bf(float f) {
  __hip_bfloat16 h = __float2bfloat16(f);
  return *reinterpret_cast<short*>(&h);
}
__device__ __forceinline__ float bf2f(short s) {
  union { unsigned u; float f; } cv;
  cv.u = ((unsigned)(unsigned short)s) << 16;
  return cv.f;
}

__device__ __forceinline__ float wave_reduce_sum(float v) {
#pragma unroll
  for (int o = 32; o; o >>= 1) v += __shfl_xor(v, o);
  return v;
}
__device__ __forceinline__ float wave_reduce_max(float v) {
#pragma unroll
  for (int o = 32; o; o >>= 1) v = fmaxf(v, __shfl_xor(v, o));
  return v;
}
__device__ __forceinline__ float block_reduce_sum(float v, float* red) {
  v = wave_reduce_sum(v);
  __syncthreads();
  if ((threadIdx.x & 63) == 0) red[threadIdx.x >> 6] = v;
  __syncthreads();
  return red[0] + red[1] + red[2] + red[3];
}
__device__ __forceinline__ float block_reduce_max(float v, float* red) {
  v = wave_reduce_max(v);
  __syncthreads();
  if ((threadIdx.x & 63) == 0) red[threadIdx.x >> 6] = v;
  __syncthreads();
  return fmaxf(fmaxf(red[0], red[1]), fmaxf(red[2], red[3]));
}

// ---- 128x128x(K) bf16 GEMM core: C = A[M,K] * Bm[N,K]^T, 4 waves, 16x16x32 MFMA
__device__ __forceinline__ void gemm_core(const short* __restrict__ A,
                                          const short* __restrict__ Bm,
                                          int K, long m0, long n0,
                                          short* As, short* Bs,
                                          f32x4 acc[4][4]) {
  const int tid  = threadIdx.x;
  const int lane = tid & 63;
  const int wid  = tid >> 6;
  const int wr = wid >> 1, wc = wid & 1;
  const int fr = lane & 15, fq = lane >> 4;
#pragma unroll
  for (int i = 0; i < 4; ++i)
#pragma unroll
    for (int j = 0; j < 4; ++j) acc[i][j] = (f32x4){0.f, 0.f, 0.f, 0.f};
  const int nkt = K >> 6;
  for (int kt = 0; kt < nkt; ++kt) {
    // stage A,B tiles [128 rows x 64 k] bf16 via global_load_lds (16B/lane)
#pragma unroll
    for (int c = 0; c < 4; ++c) {
      const int base = (wid * 4 + c) * 512;          // element base (wave-uniform)
      const int elem = base + lane * 8;
      const int row = elem >> 6, col = elem & 63;
      const short* ga = A  + (m0 + row) * (long)K + kt * 64 + col;
      const short* gb = Bm + (n0 + row) * (long)K + kt * 64 + col;
      __builtin_amdgcn_global_load_lds((gmem_void*)ga, (lds_void*)(As + base), 16, 0, 0);
      __builtin_amdgcn_global_load_lds((gmem_void*)gb, (lds_void*)(Bs + base), 16, 0, 0);
    }
    __syncthreads();
    const short* aB = As + (wr * 64 + fr) * 64 + fq * 8;
    const short* bB = Bs + (wc * 64 + fr) * 64 + fq * 8;
#pragma unroll
    for (int kk = 0; kk < 2; ++kk) {
      s16x8 af[4], bfr[4];
#pragma unroll
      for (int mi = 0; mi < 4; ++mi) af[mi] = *(const s16x8*)(aB + mi * 1024 + kk * 32);
#pragma unroll
      for (int ni = 0; ni < 4; ++ni) bfr[ni] = *(const s16x8*)(bB + ni * 1024 + kk * 32);
#pragma unroll
      for (int mi = 0; mi < 4; ++mi)
#pragma unroll
        for (int ni = 0; ni < 4; ++ni)
          acc[mi][ni] = __builtin_amdgcn_mfma_f32_16x16x32_bf16(af[mi], bfr[ni],
                                                                acc[mi][ni], 0, 0, 0);
    }
    __syncthreads();
  }
}

// ---- weights f32 -> bf16 (Wq,Wk,Wv concatenated)
__global__ __launch_bounds__(256) void cvtw_kernel(const float* __restrict__ Wq,
    const float* __restrict__ Wk, const float* __restrict__ Wv, short* __restrict__ out) {
  long i = ((long)blockIdx.x * 256 + threadIdx.x) * 4;
  int seg = (int)(i >> 20);
  long off = i & 1048575;
  const float* src = seg == 0 ? Wq : (seg == 1 ? Wk : Wv);
  f32x4 v = *(const f32x4*)(src + off);
  s16x4 o = { f2bf(v[0]), f2bf(v[1]), f2bf(v[2]), f2bf(v[3]) };
  *(s16x4*)(out + i) = o;
}

// ---- cond = [relu6(rel_emb[rel] @ Wrf^T + brf), 0.5*(x[sh]+x[st])]   [B, 2H]
__global__ __launch_bounds__(256) void cond_kernel(const int* __restrict__ relation,
    const float* __restrict__ x, const int* __restrict__ sub_head,
    const int* __restrict__ sub_tail, const float* __restrict__ rel_emb,
    const float* __restrict__ Wrf, const float* __restrict__ brf, float* __restrict__ cond) {
  const int b = blockIdx.x;
  const int tid = threadIdx.x;
  __shared__ float r[NH];
  const int rid = relation[b];
  for (int h = tid; h < NH; h += 256) r[h] = rel_emb[rid * NH + h];
  __syncthreads();
  const int lane = tid & 63, wid = tid >> 6;
  for (int g = wid; g < NH; g += 4) {
    float s = 0.f;
    for (int h = lane; h < NH; h += 64) s += r[h] * Wrf[(long)g * NH + h];
    s = wave_reduce_sum(s);
    if (lane == 0) cond[b * 2 * NH + g] = fminf(fmaxf(s + brf[g], 0.f), 6.f);
  }
  const int sh = sub_head[b], st = sub_tail[b];
  for (int h = tid; h < NH; h += 256)
    cond[b * 2 * NH + NH + h] =
        0.5f * (x[((long)b * NS + sh) * NH + h] + x[((long)b * NS + st) * NH + h]);
}

// ---- wln/bln[b,g] = cond[b,:] . W{wd,bd}[g,:] + cln_{w,b}[g]   (one block per g)
__global__ __launch_bounds__(256) void wb_kernel(const float* __restrict__ cond,
    const float* __restrict__ Wwd, const float* __restrict__ Wbd,
    const float* __restrict__ cln_w, const float* __restrict__ cln_b,
    float* __restrict__ wln, float* __restrict__ bln) {
  const int g = blockIdx.x;
  const int tid = threadIdx.x;
  __shared__ float wrow[2 * NH];
  __shared__ float brow[2 * NH];
  for (int i = tid; i < 2 * NH; i += 256) {
    wrow[i] = Wwd[(long)g * 2 * NH + i];
    brow[i] = Wbd[(long)g * 2 * NH + i];
  }
  __syncthreads();
  const int lane = tid & 63, wid = tid >> 6;
  const float cw = cln_w[g], cb = cln_b[g];
  for (int b = wid; b < NB; b += 4) {
    float sw = 0.f, sb = 0.f;
    for (int c = lane; c < 2 * NH; c += 64) {
      float cv = cond[b * 2 * NH + c];
      sw += cv * wrow[c];
      sb += cv * brow[c];
    }
    sw = wave_reduce_sum(sw);
    sb = wave_reduce_sum(sb);
    if (lane == 0) {
      wln[b * NH + g] = sw + cw;
      bln[b * NH + g] = sb + cb;
    }
  }
}

// ---- conditional LayerNorm -> normed (bf16)
__global__ __launch_bounds__(256) void ln_kernel(const float* __restrict__ x,
    const float* __restrict__ wln, const float* __restrict__ bln, short* __restrict__ normed) {
  const long row = blockIdx.x;
  const int tid = threadIdx.x;
  const long b = row >> 10;
  __shared__ float red[4];
  f32x4 v = *(const f32x4*)(x + row * NH + tid * 4);
  float mean = block_reduce_sum(v[0] + v[1] + v[2] + v[3], red) * (1.f / NH);
  float c0 = v[0] - mean, c1 = v[1] - mean, c2 = v[2] - mean, c3 = v[3] - mean;
  float var = block_reduce_sum(c0 * c0 + c1 * c1 + c2 * c2 + c3 * c3, red) * (1.f / NH);
  float rstd = rsqrtf(var + 1e-12f);
  f32x4 wv = *(const f32x4*)(wln + b * NH + tid * 4);
  f32x4 bv = *(const f32x4*)(bln + b * NH + tid * 4);
  s16x4 o = { f2bf(c0 * rstd * wv[0] + bv[0]), f2bf(c1 * rstd * wv[1] + bv[1]),
              f2bf(c2 * rstd * wv[2] + bv[2]), f2bf(c3 * rstd * wv[3] + bv[3]) };
  *(s16x4*)(normed + row * NH + tid * 4) = o;
}

// ---- q/k/v = relu(normed @ W^T + b); v stored transposed vT[b][h][t]
__global__ __launch_bounds__(256) void qkv_kernel(const short* __restrict__ A,
    const short* __restrict__ Wqb, const short* __restrict__ Wkb, const short* __restrict__ Wvb,
    const float* __restrict__ bq, const float* __restrict__ bk, const float* __restrict__ bv,
    short* __restrict__ q, short* __restrict__ k, short* __restrict__ vT) {
  __shared__ short As[8192], Bs[8192];
  const int z = blockIdx.z;
  const short* W = z == 0 ? Wqb : (z == 1 ? Wkb : Wvb);
  const float* bias = z == 0 ? bq : (z == 1 ? bk : bv);
  const long m0 = (long)blockIdx.x * 128;
  const long n0 = (long)blockIdx.y * 128;
  f32x4 acc[4][4];
  gemm_core(A, W, NH, m0, n0, As, Bs, acc);
  const int lane = threadIdx.x & 63, wid = threadIdx.x >> 6;
  const int wr = wid >> 1, wc = wid & 1, fr = lane & 15, fq = lane >> 4;
#pragma unroll
  for (int mi = 0; mi < 4; ++mi)
#pragma unroll
    for (int ni = 0; ni < 4; ++ni) {
      const long col = n0 + wc * 64 + ni * 16 + fr;
      const float bcol = bias[col];
#pragma unroll
      for (int r = 0; r < 4; ++r) {
        const long row = m0 + wr * 64 + mi * 16 + fq * 4 + r;
        float val = fmaxf(acc[mi][ni][r] + bcol, 0.f);
        short sv = f2bf(val);
        if (z == 0)      q[row * NH + col] = sv;
        else if (z == 1) k[row * NH + col] = sv;
        else {
          const long bb = row >> 10, t = row & 1023;
          vT[(bb * NH + col) * NS + t] = sv;
        }
      }
    }
}

// ---- e[b,s,t] = q[b,s,:] . k[b,t,:] - 1e10*(1-mask[b,t])   (f32)
__global__ __launch_bounds__(256) void escore_kernel(const short* __restrict__ q,
    const short* __restrict__ k, const int* __restrict__ amask, float* __restrict__ e) {
  __shared__ short As[8192], Bs[8192];
  const int b = blockIdx.z;
  const short* A  = q + (long)b * NS * NH;
  const short* Bm = k + (long)b * NS * NH;
  const long m0 = (long)blockIdx.x * 128;
  const long n0 = (long)blockIdx.y * 128;
  f32x4 acc[4][4];
  gemm_core(A, Bm, NH, m0, n0, As, Bs, acc);
  const int lane = threadIdx.x & 63, wid = threadIdx.x >> 6;
  const int wr = wid >> 1, wc = wid & 1, fr = lane & 15, fq = lane >> 4;
  float* eb = e + (long)b * NS * NS;
#pragma unroll
  for (int mi = 0; mi < 4; ++mi)
#pragma unroll
    for (int ni = 0; ni < 4; ++ni) {
      const long col = n0 + wc * 64 + ni * 16 + fr;
      const float mb = -1e10f * (1.f - (float)amask[b * NS + col]);
#pragma unroll
      for (int r = 0; r < 4; ++r) {
        const long row = m0 + wr * 64 + mi * 16 + fq * 4 + r;
        eb[row * NS + col] = acc[mi][ni][r] + mb;
      }
    }
}

// ---- row softmax: a = bf16(exp(e - max)) (unnormalized), inv_sum = 1/sum
__global__ __launch_bounds__(256) void softmax_kernel(const float* __restrict__ e,
    short* __restrict__ a, float* __restrict__ inv_sum) {
  const long row = blockIdx.x;
  const int tid = threadIdx.x;
  __shared__ float red[4];
  f32x4 v = *(const f32x4*)(e + row * NS + tid * 4);
  float m = block_reduce_max(fmaxf(fmaxf(v[0], v[1]), fmaxf(v[2], v[3])), red);
  float p0 = expf(v[0] - m), p1 = expf(v[1] - m);
  float p2 = expf(v[2] - m), p3 = expf(v[3] - m);
  float s = block_reduce_sum(p0 + p1 + p2 + p3, red);
  s16x4 o = { f2bf(p0), f2bf(p1), f2bf(p2), f2bf(p3) };
  *(s16x4*)(a + row * NS + tid * 4) = o;
  if (tid == 0) inv_sum[row] = 1.f / s;
}

// ---- hidden = (a @ v) * inv_sum + normed   (f32, into d_out)
__global__ __launch_bounds__(256) void av_kernel(const short* __restrict__ a,
    const short* __restrict__ vT, const float* __restrict__ inv_sum,
    const short* __restrict__ normed, float* __restrict__ hid) {
  __shared__ short As[8192], Bs[8192];
  const int b = blockIdx.z;
  const short* A  = a  + (long)b * NS * NS;
  const short* Bm = vT + (long)b * NH * NS;
  const long m0 = (long)blockIdx.x * 128;
  const long n0 = (long)blockIdx.y * 128;
  f32x4 acc[4][4];
  gemm_core(A, Bm, NS, m0, n0, As, Bs, acc);
  const int lane = threadIdx.x & 63, wid = threadIdx.x >> 6;
  const int wr = wid >> 1, wc = wid & 1, fr = lane & 15, fq = lane >> 4;
#pragma unroll
  for (int mi = 0; mi < 4; ++mi)
#pragma unroll
    for (int ni = 0; ni < 4; ++ni) {
      const long col = n0 + wc * 64 + ni * 16 + fr;
#pragma unroll
      for (int r = 0; r < 4; ++r) {
        const long row = m0 + wr * 64 + mi * 16 + fq * 4 + r;
        const long gi = ((long)b * NS + row) * NH + col;
        hid[gi] = acc[mi][ni][r] * inv_sum[b * NS + row] + bf2f(normed[gi]);
      }
    }
}

// ---- pred[b,s] = hidden[b,s,:] . Wo + bo
__global__ __launch_bounds__(256) void pred_kernel(const float* __restrict__ hid,
    const float* __restrict__ Wo, const float* __restrict__ bo, float* __restrict__ pred) {
  const int row = blockIdx.x * 4 + (threadIdx.x >> 6);
  const int lane = threadIdx.x & 63;
  const float* hr = hid + (long)row * NH;
  float s = 0.f;
#pragma unroll
  for (int i = 0; i < 4; ++i) {
    f32x4 hv = *(const f32x4*)(hr + i * 256 + lane * 4);
    f32x4 wv = *(const f32x4*)(Wo + i * 256 + lane * 4);
    s += hv[0] * wv[0] + hv[1] * wv[1] + hv[2] * wv[2] + hv[3] * wv[3];
  }
  s = wave_reduce_sum(s);
  if (lane == 0) pred[row] = s + bo[0];
}

extern "C" void kernel_launch(void* const* d_in, const int* in_sizes, int n_in,
                              void* d_out, int out_size, void* d_ws, size_t ws_size,
                              hipStream_t stream) {
  (void)in_sizes; (void)n_in; (void)out_size; (void)ws_size;
  const int*   relation = (const int*)d_in[0];
  const float* x        = (const float*)d_in[1];
  const int*   sub_head = (const int*)d_in[2];
  const int*   sub_tail = (const int*)d_in[3];
  const int*   amask    = (const int*)d_in[4];
  const float* rel_emb  = (const float*)d_in[5];
  const float* Wrf      = (const float*)d_in[6];
  const float* brf      = (const float*)d_in[7];
  const float* cln_w    = (const float*)d_in[8];
  const float* cln_b    = (const float*)d_in[9];
  const float* Wwd      = (const float*)d_in[10];
  const float* Wbd      = (const float*)d_in[11];
  const float* Wq       = (const float*)d_in[12];
  const float* bq       = (const float*)d_in[13];
  const float* Wk       = (const float*)d_in[14];
  const float* bk       = (const float*)d_in[15];
  const float* Wv       = (const float*)d_in[16];
  const float* bv       = (const float*)d_in[17];
  const float* Wo       = (const float*)d_in[18];
  const float* bo       = (const float*)d_in[19];

  char* ws = (char*)d_ws;
  short* wq_bf = (short*)ws;                 // 1M shorts
  short* wk_bf = wq_bf + 1048576;
  short* wv_bf = wk_bf + 1048576;
  float* cond    = (float*)(ws + 6291456);   // [32, 2048]
  float* wln     = cond + 32 * 2048;         // [32, 1024]
  float* bln     = wln + 32 * 1024;          // [32, 1024]
  float* inv_sum = bln + 32 * 1024;          // [32768]
  short* normed  = (short*)(inv_sum + 32768);        // 33.5M bf16
  short* qb      = normed + 33554432;                // q, later reused as 'a'
  short* kb      = qb + 33554432;
  short* vT      = kb + 33554432;                    // transposed v
  float* e       = (float*)(vT + 33554432);          // 33.5M f32

  float* pred = (float*)d_out;
  float* hid  = pred + 32768;

  cvtw_kernel<<<3072, 256, 0, stream>>>(Wq, Wk, Wv, wq_bf);
  cond_kernel<<<NB, 256, 0, stream>>>(relation, x, sub_head, sub_tail, rel_emb, Wrf, brf, cond);
  wb_kernel<<<NH, 256, 0, stream>>>(cond, Wwd, Wbd, cln_w, cln_b, wln, bln);
  ln_kernel<<<NB * NS, 256, 0, stream>>>(x, wln, bln, normed);
  qkv_kernel<<<dim3(256, 8, 3), 256, 0, stream>>>(normed, wq_bf, wk_bf, wv_bf,
                                                  bq, bk, bv, qb, kb, vT);
  escore_kernel<<<dim3(8, 8, 32), 256, 0, stream>>>(qb, kb, amask, e);
  softmax_kernel<<<NB * NS, 256, 0, stream>>>(e, qb, inv_sum);
  av_kernel<<<dim3(8, 8, 32), 256, 0, stream>>>(qb, vT, inv_sum, normed, hid);
  pred_kernel<<<NB * NS / 4, 256, 0, stream>>>(hid, Wo, bo, pred);
}

// Round 2
// 840.412 us; speedup vs baseline: 2.8017x; 2.8017x over previous
//
#include <hip/hip_runtime.h>
#include <hip/hip_bf16.h>

#define NB 32
#define NS 1024
#define NH 1024

typedef short s16x4 __attribute__((ext_vector_type(4)));
typedef short s16x8 __attribute__((ext_vector_type(8)));
typedef float f32x4 __attribute__((ext_vector_type(4)));

typedef __attribute__((address_space(3))) void lds_void;
typedef const __attribute__((address_space(1))) void gmem_void;

__device__ __forceinline__ short f2bf(float f) {
  __hip_bfloat16 h = __float2bfloat16(f);
  return *reinterpret_cast<short*>(&h);
}
__device__ __forceinline__ float bf2f(short s) {
  union { unsigned u; float f; } cv;
  cv.u = ((unsigned)(unsigned short)s) << 16;
  return cv.f;
}

__device__ __forceinline__ float wave_reduce_sum(float v) {
#pragma unroll
  for (int o = 32; o; o >>= 1) v += __shfl_xor(v, o);
  return v;
}
__device__ __forceinline__ float wave_reduce_max(float v) {
#pragma unroll
  for (int o = 32; o; o >>= 1) v = fmaxf(v, __shfl_xor(v, o));
  return v;
}
__device__ __forceinline__ float block_reduce_sum(float v, float* red) {
  v = wave_reduce_sum(v);
  __syncthreads();
  if ((threadIdx.x & 63) == 0) red[threadIdx.x >> 6] = v;
  __syncthreads();
  return red[0] + red[1] + red[2] + red[3];
}
__device__ __forceinline__ float block_reduce_max(float v, float* red) {
  v = wave_reduce_max(v);
  __syncthreads();
  if ((threadIdx.x & 63) == 0) red[threadIdx.x >> 6] = v;
  __syncthreads();
  return fmaxf(fmaxf(red[0], red[1]), fmaxf(red[2], red[3]));
}

// ---- 128x128x(K) bf16 GEMM core: C = A[M,K] * Bm[N,K]^T, 4 waves, 16x16x32 MFMA
__device__ __forceinline__ void gemm_core(const short* __restrict__ A,
                                          const short* __restrict__ Bm,
                                          int K, long m0, long n0,
                                          short* As, short* Bs,
                                          f32x4 acc[4][4]) {
  const int tid  = threadIdx.x;
  const int lane = tid & 63;
  const int wid  = tid >> 6;
  const int wr = wid >> 1, wc = wid & 1;
  const int fr = lane & 15, fq = lane >> 4;
#pragma unroll
  for (int i = 0; i < 4; ++i)
#pragma unroll
    for (int j = 0; j < 4; ++j) acc[i][j] = (f32x4){0.f, 0.f, 0.f, 0.f};
  const int nkt = K >> 6;
  for (int kt = 0; kt < nkt; ++kt) {
    // stage A,B tiles [128 rows x 64 k] bf16 via global_load_lds (16B/lane)
#pragma unroll
    for (int c = 0; c < 4; ++c) {
      const int base = (wid * 4 + c) * 512;          // element base (wave-uniform)
      const int elem = base + lane * 8;
      const int row = elem >> 6, col = elem & 63;
      const short* ga = A  + (m0 + row) * (long)K + kt * 64 + col;
      const short* gb = Bm + (n0 + row) * (long)K + kt * 64 + col;
      __builtin_amdgcn_global_load_lds((gmem_void*)ga, (lds_void*)(As + base), 16, 0, 0);
      __builtin_amdgcn_global_load_lds((gmem_void*)gb, (lds_void*)(Bs + base), 16, 0, 0);
    }
    __syncthreads();
    const short* aB = As + (wr * 64 + fr) * 64 + fq * 8;
    const short* bB = Bs + (wc * 64 + fr) * 64 + fq * 8;
#pragma unroll
    for (int kk = 0; kk < 2; ++kk) {
      s16x8 af[4], bfr[4];
#pragma unroll
      for (int mi = 0; mi < 4; ++mi) af[mi] = *(const s16x8*)(aB + mi * 1024 + kk * 32);
#pragma unroll
      for (int ni = 0; ni < 4; ++ni) bfr[ni] = *(const s16x8*)(bB + ni * 1024 + kk * 32);
#pragma unroll
      for (int mi = 0; mi < 4; ++mi)
#pragma unroll
        for (int ni = 0; ni < 4; ++ni)
          acc[mi][ni] = __builtin_amdgcn_mfma_f32_16x16x32_bf16(af[mi], bfr[ni],
                                                                acc[mi][ni], 0, 0, 0);
    }
    __syncthreads();
  }
}

// ---- weights f32 -> bf16 (Wq,Wk,Wv concatenated)
__global__ __launch_bounds__(256) void cvtw_kernel(const float* __restrict__ Wq,
    const float* __restrict__ Wk, const float* __restrict__ Wv, short* __restrict__ out) {
  long i = ((long)blockIdx.x * 256 + threadIdx.x) * 4;
  int seg = (int)(i >> 20);
  long off = i & 1048575;
  const float* src = seg == 0 ? Wq : (seg == 1 ? Wk : Wv);
  f32x4 v = *(const f32x4*)(src + off);
  s16x4 o = { f2bf(v[0]), f2bf(v[1]), f2bf(v[2]), f2bf(v[3]) };
  *(s16x4*)(out + i) = o;
}

// ---- cond = [relu6(rel_emb[rel] @ Wrf^T + brf), 0.5*(x[sh]+x[st])]   [B, 2H]
// grid (NB, 16): block (b, gc) computes cond[b, gc*64 .. gc*64+64)
__global__ __launch_bounds__(256) void cond_kernel(const int* __restrict__ relation,
    const float* __restrict__ x, const int* __restrict__ sub_head,
    const int* __restrict__ sub_tail, const float* __restrict__ rel_emb,
    const float* __restrict__ Wrf, const float* __restrict__ brf, float* __restrict__ cond) {
  const int b = blockIdx.x;
  const int gc = blockIdx.y;
  const int tid = threadIdx.x;
  __shared__ float r[NH];
  const int rid = relation[b];
  for (int h = tid * 4; h < NH; h += 1024)
    *(f32x4*)(r + h) = *(const f32x4*)(rel_emb + (long)rid * NH + h);
  if (gc == 0) {
    const int sh = sub_head[b], st = sub_tail[b];
    for (int h = tid * 4; h < NH; h += 1024) {
      f32x4 a = *(const f32x4*)(x + ((long)b * NS + sh) * NH + h);
      f32x4 c = *(const f32x4*)(x + ((long)b * NS + st) * NH + h);
      f32x4 o = { 0.5f * (a[0] + c[0]), 0.5f * (a[1] + c[1]),
                  0.5f * (a[2] + c[2]), 0.5f * (a[3] + c[3]) };
      *(f32x4*)(cond + b * 2 * NH + NH + h) = o;
    }
  }
  __syncthreads();
  const int lane = tid & 63, wid = tid >> 6;
#pragma unroll
  for (int gi = 0; gi < 16; ++gi) {
    const int g = gc * 64 + wid * 16 + gi;
    float s = 0.f;
#pragma unroll
    for (int h = lane * 4; h < NH; h += 256) {
      f32x4 wv = *(const f32x4*)(Wrf + (long)g * NH + h);
      f32x4 rv = *(const f32x4*)(r + h);
      s += wv[0] * rv[0] + wv[1] * rv[1] + wv[2] * rv[2] + wv[3] * rv[3];
    }
    s = wave_reduce_sum(s);
    if (lane == 0) cond[b * 2 * NH + g] = fminf(fmaxf(s + brf[g], 0.f), 6.f);
  }
}

// ---- wln/bln[b,g] = cond[b,:] . W{wd,bd}[g,:] + cln_{w,b}[g]   (one block per g)
__global__ __launch_bounds__(256) void wb_kernel(const float* __restrict__ cond,
    const float* __restrict__ Wwd, const float* __restrict__ Wbd,
    const float* __restrict__ cln_w, const float* __restrict__ cln_b,
    float* __restrict__ wln, float* __restrict__ bln) {
  const int g = blockIdx.x;
  const int tid = threadIdx.x;
  __shared__ float wrow[2 * NH];
  __shared__ float brow[2 * NH];
  for (int i = tid * 4; i < 2 * NH; i += 1024) {
    *(f32x4*)(wrow + i) = *(const f32x4*)(Wwd + (long)g * 2 * NH + i);
    *(f32x4*)(brow + i) = *(const f32x4*)(Wbd + (long)g * 2 * NH + i);
  }
  __syncthreads();
  const int lane = tid & 63, wid = tid >> 6;
  const float cw = cln_w[g], cb = cln_b[g];
  for (int b = wid; b < NB; b += 4) {
    float sw = 0.f, sb = 0.f;
#pragma unroll
    for (int c = lane * 4; c < 2 * NH; c += 256) {
      f32x4 cv = *(const f32x4*)(cond + b * 2 * NH + c);
      f32x4 wv = *(const f32x4*)(wrow + c);
      f32x4 bv = *(const f32x4*)(brow + c);
      sw += cv[0] * wv[0] + cv[1] * wv[1] + cv[2] * wv[2] + cv[3] * wv[3];
      sb += cv[0] * bv[0] + cv[1] * bv[1] + cv[2] * bv[2] + cv[3] * bv[3];
    }
    sw = wave_reduce_sum(sw);
    sb = wave_reduce_sum(sb);
    if (lane == 0) {
      wln[b * NH + g] = sw + cw;
      bln[b * NH + g] = sb + cb;
    }
  }
}

// ---- conditional LayerNorm -> normed (bf16)
__global__ __launch_bounds__(256) void ln_kernel(const float* __restrict__ x,
    const float* __restrict__ wln, const float* __restrict__ bln, short* __restrict__ normed) {
  const long row = blockIdx.x;
  const int tid = threadIdx.x;
  const long b = row >> 10;
  __shared__ float red[4];
  f32x4 v = *(const f32x4*)(x + row * NH + tid * 4);
  float mean = block_reduce_sum(v[0] + v[1] + v[2] + v[3], red) * (1.f / NH);
  float c0 = v[0] - mean, c1 = v[1] - mean, c2 = v[2] - mean, c3 = v[3] - mean;
  float var = block_reduce_sum(c0 * c0 + c1 * c1 + c2 * c2 + c3 * c3, red) * (1.f / NH);
  float rstd = rsqrtf(var + 1e-12f);
  f32x4 wv = *(const f32x4*)(wln + b * NH + tid * 4);
  f32x4 bv = *(const f32x4*)(bln + b * NH + tid * 4);
  s16x4 o = { f2bf(c0 * rstd * wv[0] + bv[0]), f2bf(c1 * rstd * wv[1] + bv[1]),
              f2bf(c2 * rstd * wv[2] + bv[2]), f2bf(c3 * rstd * wv[3] + bv[3]) };
  *(s16x4*)(normed + row * NH + tid * 4) = o;
}

// ---- q/k/v = relu(normed @ W^T + b); v stored transposed vT[b][h][t]
__global__ __launch_bounds__(256) void qkv_kernel(const short* __restrict__ A,
    const short* __restrict__ Wqb, const short* __restrict__ Wkb, const short* __restrict__ Wvb,
    const float* __restrict__ bq, const float* __restrict__ bk, const float* __restrict__ bv,
    short* __restrict__ q, short* __restrict__ k, short* __restrict__ vT) {
  __shared__ short As[8192], Bs[8192];
  const int z = blockIdx.z;
  const short* W = z == 0 ? Wqb : (z == 1 ? Wkb : Wvb);
  const float* bias = z == 0 ? bq : (z == 1 ? bk : bv);
  const long m0 = (long)blockIdx.x * 128;
  const long n0 = (long)blockIdx.y * 128;
  f32x4 acc[4][4];
  gemm_core(A, W, NH, m0, n0, As, Bs, acc);
  const int lane = threadIdx.x & 63, wid = threadIdx.x >> 6;
  const int wr = wid >> 1, wc = wid & 1, fr = lane & 15, fq = lane >> 4;
#pragma unroll
  for (int mi = 0; mi < 4; ++mi)
#pragma unroll
    for (int ni = 0; ni < 4; ++ni) {
      const long col = n0 + wc * 64 + ni * 16 + fr;
      const float bcol = bias[col];
#pragma unroll
      for (int r = 0; r < 4; ++r) {
        const long row = m0 + wr * 64 + mi * 16 + fq * 4 + r;
        float val = fmaxf(acc[mi][ni][r] + bcol, 0.f);
        short sv = f2bf(val);
        if (z == 0)      q[row * NH + col] = sv;
        else if (z == 1) k[row * NH + col] = sv;
        else {
          const long bb = row >> 10, t = row & 1023;
          vT[(bb * NH + col) * NS + t] = sv;
        }
      }
    }
}

// ---- e[b,s,t] = q[b,s,:] . k[b,t,:] - 1e10*(1-mask[b,t])   (f32)
__global__ __launch_bounds__(256) void escore_kernel(const short* __restrict__ q,
    const short* __restrict__ k, const int* __restrict__ amask, float* __restrict__ e) {
  __shared__ short As[8192], Bs[8192];
  const int b = blockIdx.z;
  const short* A  = q + (long)b * NS * NH;
  const short* Bm = k + (long)b * NS * NH;
  const long m0 = (long)blockIdx.x * 128;
  const long n0 = (long)blockIdx.y * 128;
  f32x4 acc[4][4];
  gemm_core(A, Bm, NH, m0, n0, As, Bs, acc);
  const int lane = threadIdx.x & 63, wid = threadIdx.x >> 6;
  const int wr = wid >> 1, wc = wid & 1, fr = lane & 15, fq = lane >> 4;
  float* eb = e + (long)b * NS * NS;
#pragma unroll
  for (int mi = 0; mi < 4; ++mi)
#pragma unroll
    for (int ni = 0; ni < 4; ++ni) {
      const long col = n0 + wc * 64 + ni * 16 + fr;
      const float mb = -1e10f * (1.f - (float)amask[b * NS + col]);
#pragma unroll
      for (int r = 0; r < 4; ++r) {
        const long row = m0 + wr * 64 + mi * 16 + fq * 4 + r;
        eb[row * NS + col] = acc[mi][ni][r] + mb;
      }
    }
}

// ---- row softmax: a = bf16(exp(e - max)) (unnormalized), inv_sum = 1/sum
__global__ __launch_bounds__(256) void softmax_kernel(const float* __restrict__ e,
    short* __restrict__ a, float* __restrict__ inv_sum) {
  const long row = blockIdx.x;
  const int tid = threadIdx.x;
  __shared__ float red[4];
  f32x4 v = *(const f32x4*)(e + row * NS + tid * 4);
  float m = block_reduce_max(fmaxf(fmaxf(v[0], v[1]), fmaxf(v[2], v[3])), red);
  float p0 = expf(v[0] - m), p1 = expf(v[1] - m);
  float p2 = expf(v[2] - m), p3 = expf(v[3] - m);
  float s = block_reduce_sum(p0 + p1 + p2 + p3, red);
  s16x4 o = { f2bf(p0), f2bf(p1), f2bf(p2), f2bf(p3) };
  *(s16x4*)(a + row * NS + tid * 4) = o;
  if (tid == 0) inv_sum[row] = 1.f / s;
}

// ---- hidden = (a @ v) * inv_sum + normed   (f32, into d_out)
__global__ __launch_bounds__(256) void av_kernel(const short* __restrict__ a,
    const short* __restrict__ vT, const float* __restrict__ inv_sum,
    const short* __restrict__ normed, float* __restrict__ hid) {
  __shared__ short As[8192], Bs[8192];
  const int b = blockIdx.z;
  const short* A  = a  + (long)b * NS * NS;
  const short* Bm = vT + (long)b * NH * NS;
  const long m0 = (long)blockIdx.x * 128;
  const long n0 = (long)blockIdx.y * 128;
  f32x4 acc[4][4];
  gemm_core(A, Bm, NS, m0, n0, As, Bs, acc);
  const int lane = threadIdx.x & 63, wid = threadIdx.x >> 6;
  const int wr = wid >> 1, wc = wid & 1, fr = lane & 15, fq = lane >> 4;
#pragma unroll
  for (int mi = 0; mi < 4; ++mi)
#pragma unroll
    for (int ni = 0; ni < 4; ++ni) {
      const long col = n0 + wc * 64 + ni * 16 + fr;
#pragma unroll
      for (int r = 0; r < 4; ++r) {
        const long row = m0 + wr * 64 + mi * 16 + fq * 4 + r;
        const long gi = ((long)b * NS + row) * NH + col;
        hid[gi] = acc[mi][ni][r] * inv_sum[b * NS + row] + bf2f(normed[gi]);
      }
    }
}

// ---- pred[b,s] = hidden[b,s,:] . Wo + bo
__global__ __launch_bounds__(256) void pred_kernel(const float* __restrict__ hid,
    const float* __restrict__ Wo, const float* __restrict__ bo, float* __restrict__ pred) {
  const int row = blockIdx.x * 4 + (threadIdx.x >> 6);
  const int lane = threadIdx.x & 63;
  const float* hr = hid + (long)row * NH;
  float s = 0.f;
#pragma unroll
  for (int i = 0; i < 4; ++i) {
    f32x4 hv = *(const f32x4*)(hr + i * 256 + lane * 4);
    f32x4 wv = *(const f32x4*)(Wo + i * 256 + lane * 4);
    s += hv[0] * wv[0] + hv[1] * wv[1] + hv[2] * wv[2] + hv[3] * wv[3];
  }
  s = wave_reduce_sum(s);
  if (lane == 0) pred[row] = s + bo[0];
}

extern "C" void kernel_launch(void* const* d_in, const int* in_sizes, int n_in,
                              void* d_out, int out_size, void* d_ws, size_t ws_size,
                              hipStream_t stream) {
  (void)in_sizes; (void)n_in; (void)out_size; (void)ws_size;
  const int*   relation = (const int*)d_in[0];
  const float* x        = (const float*)d_in[1];
  const int*   sub_head = (const int*)d_in[2];
  const int*   sub_tail = (const int*)d_in[3];
  const int*   amask    = (const int*)d_in[4];
  const float* rel_emb  = (const float*)d_in[5];
  const float* Wrf      = (const float*)d_in[6];
  const float* brf      = (const float*)d_in[7];
  const float* cln_w    = (const float*)d_in[8];
  const float* cln_b    = (const float*)d_in[9];
  const float* Wwd      = (const float*)d_in[10];
  const float* Wbd      = (const float*)d_in[11];
  const float* Wq       = (const float*)d_in[12];
  const float* bq       = (const float*)d_in[13];
  const float* Wk       = (const float*)d_in[14];
  const float* bk       = (const float*)d_in[15];
  const float* Wv       = (const float*)d_in[16];
  const float* bv       = (const float*)d_in[17];
  const float* Wo       = (const float*)d_in[18];
  const float* bo       = (const float*)d_in[19];

  char* ws = (char*)d_ws;
  short* wq_bf = (short*)ws;                 // 1M shorts
  short* wk_bf = wq_bf + 1048576;
  short* wv_bf = wk_bf + 1048576;
  float* cond    = (float*)(ws + 6291456);   // [32, 2048]
  float* wln     = cond + 32 * 2048;         // [32, 1024]
  float* bln     = wln + 32 * 1024;          // [32, 1024]
  float* inv_sum = bln + 32 * 1024;          // [32768]
  short* normed  = (short*)(inv_sum + 32768);        // 33.5M bf16
  short* qb      = normed + 33554432;                // q, later reused as 'a'
  short* kb      = qb + 33554432;
  short* vT      = kb + 33554432;                    // transposed v
  float* e       = (float*)(vT + 33554432);          // 33.5M f32

  float* pred = (float*)d_out;
  float* hid  = pred + 32768;

  cvtw_kernel<<<3072, 256, 0, stream>>>(Wq, Wk, Wv, wq_bf);
  cond_kernel<<<dim3(NB, 16), 256, 0, stream>>>(relation, x, sub_head, sub_tail,
                                                rel_emb, Wrf, brf, cond);
  wb_kernel<<<NH, 256, 0, stream>>>(cond, Wwd, Wbd, cln_w, cln_b, wln, bln);
  ln_kernel<<<NB * NS, 256, 0, stream>>>(x, wln, bln, normed);
  qkv_kernel<<<dim3(256, 8, 3), 256, 0, stream>>>(normed, wq_bf, wk_bf, wv_bf,
                                                  bq, bk, bv, qb, kb, vT);
  escore_kernel<<<dim3(8, 8, 32), 256, 0, stream>>>(qb, kb, amask, e);
  softmax_kernel<<<NB * NS, 256, 0, stream>>>(e, qb, inv_sum);
  av_kernel<<<dim3(8, 8, 32), 256, 0, stream>>>(qb, vT, inv_sum, normed, hid);
  pred_kernel<<<NB * NS / 4, 256, 0, stream>>>(hid, Wo, bo, pred);
}

// Round 3
// 581.898 us; speedup vs baseline: 4.0464x; 1.4443x over previous
//
#include <hip/hip_runtime.h>
#include <hip/hip_bf16.h>

#define NB 32
#define NS 1024
#define NH 1024

typedef short s16x4 __attribute__((ext_vector_type(4)));
typedef short s16x8 __attribute__((ext_vector_type(8)));
typedef float f32x4 __attribute__((ext_vector_type(4)));

typedef __attribute__((address_space(3))) void lds_void;
typedef const __attribute__((address_space(1))) void gmem_void;

__device__ __forceinline__ short f2bf(float f) {
  __hip_bfloat16 h = __float2bfloat16(f);
  return *reinterpret_cast<short*>(&h);
}
__device__ __forceinline__ float bf2f(short s) {
  union { unsigned u; float f; } cv;
  cv.u = ((unsigned)(unsigned short)s) << 16;
  return cv.f;
}

__device__ __forceinline__ float wave_reduce_sum(float v) {
#pragma unroll
  for (int o = 32; o; o >>= 1) v += __shfl_xor(v, o);
  return v;
}
__device__ __forceinline__ float wave_reduce_max(float v) {
#pragma unroll
  for (int o = 32; o; o >>= 1) v = fmaxf(v, __shfl_xor(v, o));
  return v;
}
__device__ __forceinline__ float block_reduce_sum(float v, float* red) {
  v = wave_reduce_sum(v);
  __syncthreads();
  if ((threadIdx.x & 63) == 0) red[threadIdx.x >> 6] = v;
  __syncthreads();
  return red[0] + red[1] + red[2] + red[3];
}
__device__ __forceinline__ float block_reduce_max(float v, float* red) {
  v = wave_reduce_max(v);
  __syncthreads();
  if ((threadIdx.x & 63) == 0) red[threadIdx.x >> 6] = v;
  __syncthreads();
  return fmaxf(fmaxf(red[0], red[1]), fmaxf(red[2], red[3]));
}

// ==================== 256x256 8-phase bf16 GEMM core ====================
// C = A[M,1024] * B[N,1024]^T. 512 threads = 8 waves (2M x 4N).
// Per wave: 128x64 output = acc[8][4] (16x16 frags). BK=64, 2 K-tiles/iter,
// double-buffered LDS (128 KiB), st-swizzled (col8 ^= row&7) on both the
// global_load_lds SOURCE and the ds_read address (rule #21 involution).
// vmcnt(4) only at phases 4/8; stages offset >=1 barrier-pair after the
// target slot's last read (see schedule comments).

#define BAR1 do { __builtin_amdgcn_s_barrier();                              \
                  asm volatile("s_waitcnt lgkmcnt(0)" ::: "memory");         \
                  __builtin_amdgcn_sched_barrier(0); } while (0)
#define BAR2 do { __builtin_amdgcn_s_barrier();                              \
                  asm volatile("" ::: "memory"); } while (0)
#define VW   asm volatile("s_waitcnt vmcnt(4)" ::: "memory")

#define GEMM_PRE()                                                           \
  __shared__ short lds[65536];                                               \
  const int tid  = threadIdx.x;                                              \
  const int lane = tid & 63;                                                 \
  const int w    = tid >> 6;                                                 \
  const int wm   = w >> 2, wn = w & 3;                                       \
  const int fr   = lane & 15, fq = lane >> 4;                                \
  /* per-thread stage source offset: row(tid>>3)*K + swizzled col */         \
  const long tA  = (long)(tid >> 3) * 1024 +                                 \
                   (((tid & 7) ^ ((tid >> 3) & 7)) << 3);                    \
  /* swizzled k-col byte offsets for ds_read (elements) */                   \
  const int kc0  = (fq * 8) ^ ((fr & 7) * 8);                                \
  const int kc1  = (fq * 8 + 32) ^ ((fr & 7) * 8);                           \
  const int rdA  = wm * 8192 + fr * 64;                                      \
  const int rdB  = 16384 + (wn >> 1) * 8192 + (wn & 1) * 4096 + fr * 64;     \
  const int wsl  = w * 512;                                                  \
  f32x4 acc[8][4];                                                           \
  s16x8 aF[4][2], bF[2][2][2];                                               \
  _Pragma("unroll") for (int i_ = 0; i_ < 8; ++i_)                           \
    _Pragma("unroll") for (int j_ = 0; j_ < 4; ++j_)                         \
      acc[i_][j_] = (f32x4){0.f, 0.f, 0.f, 0.f};

// stage one 128x64 half-tile (2 x global_load_lds of 8KB rounds)
#define STAGE(d, isB, h, kt)                                                 \
  do {                                                                       \
    const short* _g = ((isB) ? gB + (n0 + (h) * 128) * 1024                  \
                             : gA + (m0 + (h) * 128) * 1024) +               \
                      (long)((kt) & 15) * 64 + tA;                           \
    short* _l = lds + (d) * 32768 + (isB) * 16384 + (h) * 8192 + wsl;        \
    __builtin_amdgcn_global_load_lds((gmem_void*)_g, (lds_void*)_l,          \
                                     16, 0, 0);                              \
    __builtin_amdgcn_global_load_lds((gmem_void*)(_g + 65536),               \
                                     (lds_void*)(_l + 4096), 16, 0, 0);      \
  } while (0)

#define RD_A(d, mq)                                                          \
  _Pragma("unroll") for (int mi = 0; mi < 4; ++mi) {                         \
    aF[mi][0] = *(const s16x8*)(lds + (d) * 32768 + rdA + (mq) * 4096 +      \
                                mi * 1024 + kc0);                            \
    aF[mi][1] = *(const s16x8*)(lds + (d) * 32768 + rdA + (mq) * 4096 +      \
                                mi * 1024 + kc1);                            \
  }
#define RD_B(d, nq)                                                          \
  _Pragma("unroll") for (int ni = 0; ni < 2; ++ni) {                         \
    bF[nq][ni][0] = *(const s16x8*)(lds + (d) * 32768 + rdB + (nq) * 2048 +  \
                                    ni * 1024 + kc0);                        \
    bF[nq][ni][1] = *(const s16x8*)(lds + (d) * 32768 + rdB + (nq) * 2048 +  \
                                    ni * 1024 + kc1);                        \
  }
#define MMA(mq, nq)                                                          \
  do {                                                                       \
    __builtin_amdgcn_s_setprio(1);                                           \
    _Pragma("unroll") for (int kk = 0; kk < 2; ++kk)                         \
      _Pragma("unroll") for (int mi = 0; mi < 4; ++mi)                       \
        _Pragma("unroll") for (int ni = 0; ni < 2; ++ni)                     \
          acc[(mq) * 4 + mi][(nq) * 2 + ni] =                                \
              __builtin_amdgcn_mfma_f32_16x16x32_bf16(                       \
                  aF[mi][kk], bF[nq][ni][kk],                                \
                  acc[(mq) * 4 + mi][(nq) * 2 + ni], 0, 0, 0);               \
    __builtin_amdgcn_s_setprio(0);                                           \
  } while (0)

// prologue: tile0 full + tile1 B-halves (12 loads), wait oldest 8 (tile0)
// steady iter i: consume 2i (dbuf0, ph1-4), 2i+1 (dbuf1, ph5-8)
//   ph1: A-h0(2i+1)->d1   ph2: A-h1(2i+1)->d1   (d1 A last read prev ph7)
//   ph3: B-h0(2i+2)->d0   ph4: B-h1(2i+2)->d0   (d0 B last read ph2)
//   ph5: A-h0(2i+2)->d0   ph6: A-h1(2i+2)->d0   (d0 A last read ph3)
//   ph7: B-h0(2i+3)->d1   ph8: B-h1(2i+3)->d1   (d1 B last read ph6)
// vmcnt(4)@ph4: d1 tile (prev ph7,8 + ph1,2) landed, ph3,4 in flight
// vmcnt(4)@ph8: d0 tile (ph3..6) landed, ph7,8 in flight
#define GEMM_MAIN()                                                          \
  GEMM_PRE();                                                                \
  STAGE(0, 1, 0, 0); STAGE(0, 1, 1, 0); STAGE(0, 0, 0, 0); STAGE(0, 0, 1, 0);\
  STAGE(1, 1, 0, 1); STAGE(1, 1, 1, 1);                                      \
  VW; BAR2;                                                                  \
  for (int it = 0; it < 8; ++it) {                                           \
    const int t1 = 2 * it + 1, t2 = 2 * it + 2, t3 = 2 * it + 3;             \
    RD_A(0, 0); RD_B(0, 0); STAGE(1, 0, 0, t1); BAR1; MMA(0, 0); BAR2;       \
    RD_B(0, 1);             STAGE(1, 0, 1, t1); BAR1; MMA(0, 1); BAR2;       \
    RD_A(0, 1);             STAGE(0, 1, 0, t2); BAR1; MMA(1, 1); BAR2;       \
                            STAGE(0, 1, 1, t2); BAR1; MMA(1, 0); VW; BAR2;   \
    RD_A(1, 0); RD_B(1, 0); STAGE(0, 0, 0, t2); BAR1; MMA(0, 0); BAR2;       \
    RD_B(1, 1);             STAGE(0, 0, 1, t2); BAR1; MMA(0, 1); BAR2;       \
    RD_A(1, 1);             STAGE(1, 1, 0, t3); BAR1; MMA(1, 1); BAR2;       \
                            STAGE(1, 1, 1, t3); BAR1; MMA(1, 0); VW; BAR2;   \
  }

// epilogue index map: row = m0 + wm*128 + mI*16 + fq*4 + r
//                     col = n0 + wn*64  + nI*16 + fr

// ---- weights f32 -> bf16 (Wq,Wk,Wv concatenated)
__global__ __launch_bounds__(256) void cvtw_kernel(const float* __restrict__ Wq,
    const float* __restrict__ Wk, const float* __restrict__ Wv, short* __restrict__ out) {
  long i = ((long)blockIdx.x * 256 + threadIdx.x) * 4;
  int seg = (int)(i >> 20);
  long off = i & 1048575;
  const float* src = seg == 0 ? Wq : (seg == 1 ? Wk : Wv);
  f32x4 v = *(const f32x4*)(src + off);
  s16x4 o = { f2bf(v[0]), f2bf(v[1]), f2bf(v[2]), f2bf(v[3]) };
  *(s16x4*)(out + i) = o;
}

// ---- cond = [relu6(rel_emb[rel] @ Wrf^T + brf), 0.5*(x[sh]+x[st])]   [B, 2H]
__global__ __launch_bounds__(256) void cond_kernel(const int* __restrict__ relation,
    const float* __restrict__ x, const int* __restrict__ sub_head,
    const int* __restrict__ sub_tail, const float* __restrict__ rel_emb,
    const float* __restrict__ Wrf, const float* __restrict__ brf, float* __restrict__ cond) {
  const int b = blockIdx.x;
  const int gc = blockIdx.y;
  const int tid = threadIdx.x;
  __shared__ float r[NH];
  const int rid = relation[b];
  for (int h = tid * 4; h < NH; h += 1024)
    *(f32x4*)(r + h) = *(const f32x4*)(rel_emb + (long)rid * NH + h);
  if (gc == 0) {
    const int sh = sub_head[b], st = sub_tail[b];
    for (int h = tid * 4; h < NH; h += 1024) {
      f32x4 a = *(const f32x4*)(x + ((long)b * NS + sh) * NH + h);
      f32x4 c = *(const f32x4*)(x + ((long)b * NS + st) * NH + h);
      f32x4 o = { 0.5f * (a[0] + c[0]), 0.5f * (a[1] + c[1]),
                  0.5f * (a[2] + c[2]), 0.5f * (a[3] + c[3]) };
      *(f32x4*)(cond + b * 2 * NH + NH + h) = o;
    }
  }
  __syncthreads();
  const int lane = tid & 63, wid = tid >> 6;
#pragma unroll
  for (int gi = 0; gi < 16; ++gi) {
    const int g = gc * 64 + wid * 16 + gi;
    float s = 0.f;
#pragma unroll
    for (int h = lane * 4; h < NH; h += 256) {
      f32x4 wv = *(const f32x4*)(Wrf + (long)g * NH + h);
      f32x4 rv = *(const f32x4*)(r + h);
      s += wv[0] * rv[0] + wv[1] * rv[1] + wv[2] * rv[2] + wv[3] * rv[3];
    }
    s = wave_reduce_sum(s);
    if (lane == 0) cond[b * 2 * NH + g] = fminf(fmaxf(s + brf[g], 0.f), 6.f);
  }
}

// ---- wln/bln[b,g] = cond[b,:] . W{wd,bd}[g,:] + cln_{w,b}[g]
__global__ __launch_bounds__(256) void wb_kernel(const float* __restrict__ cond,
    const float* __restrict__ Wwd, const float* __restrict__ Wbd,
    const float* __restrict__ cln_w, const float* __restrict__ cln_b,
    float* __restrict__ wln, float* __restrict__ bln) {
  const int g = blockIdx.x;
  const int tid = threadIdx.x;
  __shared__ float wrow[2 * NH];
  __shared__ float brow[2 * NH];
  for (int i = tid * 4; i < 2 * NH; i += 1024) {
    *(f32x4*)(wrow + i) = *(const f32x4*)(Wwd + (long)g * 2 * NH + i);
    *(f32x4*)(brow + i) = *(const f32x4*)(Wbd + (long)g * 2 * NH + i);
  }
  __syncthreads();
  const int lane = tid & 63, wid = tid >> 6;
  const float cw = cln_w[g], cb = cln_b[g];
  for (int b = wid; b < NB; b += 4) {
    float sw = 0.f, sb = 0.f;
#pragma unroll
    for (int c = lane * 4; c < 2 * NH; c += 256) {
      f32x4 cv = *(const f32x4*)(cond + b * 2 * NH + c);
      f32x4 wv = *(const f32x4*)(wrow + c);
      f32x4 bv = *(const f32x4*)(brow + c);
      sw += cv[0] * wv[0] + cv[1] * wv[1] + cv[2] * wv[2] + cv[3] * wv[3];
      sb += cv[0] * bv[0] + cv[1] * bv[1] + cv[2] * bv[2] + cv[3] * bv[3];
    }
    sw = wave_reduce_sum(sw);
    sb = wave_reduce_sum(sb);
    if (lane == 0) {
      wln[b * NH + g] = sw + cw;
      bln[b * NH + g] = sb + cb;
    }
  }
}

// ---- conditional LayerNorm -> normed (bf16)
__global__ __launch_bounds__(256) void ln_kernel(const float* __restrict__ x,
    const float* __restrict__ wln, const float* __restrict__ bln, short* __restrict__ normed) {
  const long row = blockIdx.x;
  const int tid = threadIdx.x;
  const long b = row >> 10;
  __shared__ float red[4];
  f32x4 v = *(const f32x4*)(x + row * NH + tid * 4);
  float mean = block_reduce_sum(v[0] + v[1] + v[2] + v[3], red) * (1.f / NH);
  float c0 = v[0] - mean, c1 = v[1] - mean, c2 = v[2] - mean, c3 = v[3] - mean;
  float var = block_reduce_sum(c0 * c0 + c1 * c1 + c2 * c2 + c3 * c3, red) * (1.f / NH);
  float rstd = rsqrtf(var + 1e-12f);
  f32x4 wv = *(const f32x4*)(wln + b * NH + tid * 4);
  f32x4 bv = *(const f32x4*)(bln + b * NH + tid * 4);
  s16x4 o = { f2bf(c0 * rstd * wv[0] + bv[0]), f2bf(c1 * rstd * wv[1] + bv[1]),
              f2bf(c2 * rstd * wv[2] + bv[2]), f2bf(c3 * rstd * wv[3] + bv[3]) };
  *(s16x4*)(normed + row * NH + tid * 4) = o;
}

// ---- q/k/v = relu(normed @ W^T + b); v stored transposed vT[b][h][t]
__global__ __launch_bounds__(512, 2) void qkv_kernel(const short* __restrict__ A,
    const short* __restrict__ Wqb, const short* __restrict__ Wkb, const short* __restrict__ Wvb,
    const float* __restrict__ bq, const float* __restrict__ bk, const float* __restrict__ bv,
    short* __restrict__ q, short* __restrict__ k, short* __restrict__ vT) {
  const int z = blockIdx.z;
  const short* gA = A;
  const short* gB = z == 0 ? Wqb : (z == 1 ? Wkb : Wvb);
  const float* bias = z == 0 ? bq : (z == 1 ? bk : bv);
  const long m0 = (long)blockIdx.x * 256;
  const long n0 = (long)blockIdx.y * 256;
  GEMM_MAIN();
#pragma unroll
  for (int mI = 0; mI < 8; ++mI)
#pragma unroll
    for (int nI = 0; nI < 4; ++nI) {
      const long col = n0 + wn * 64 + nI * 16 + fr;
      const float bcol = bias[col];
#pragma unroll
      for (int r = 0; r < 4; ++r) {
        const long row = m0 + wm * 128 + mI * 16 + fq * 4 + r;
        float val = fmaxf(acc[mI][nI][r] + bcol, 0.f);
        short sv = f2bf(val);
        if (z == 0)      q[row * NH + col] = sv;
        else if (z == 1) k[row * NH + col] = sv;
        else             vT[((row >> 10) * NH + col) * NS + (row & 1023)] = sv;
      }
    }
}

// ---- e[b,s,t] = q[b,s,:] . k[b,t,:] - 1e10*(1-mask[b,t])   (f32)
__global__ __launch_bounds__(512, 2) void escore_kernel(const short* __restrict__ q,
    const short* __restrict__ k, const int* __restrict__ amask, float* __restrict__ e) {
  const int b = blockIdx.z;
  const short* gA = q + (long)b * NS * NH;
  const short* gB = k + (long)b * NS * NH;
  const long m0 = (long)blockIdx.x * 256;
  const long n0 = (long)blockIdx.y * 256;
  GEMM_MAIN();
  float* eb = e + (long)b * NS * NS;
#pragma unroll
  for (int mI = 0; mI < 8; ++mI)
#pragma unroll
    for (int nI = 0; nI < 4; ++nI) {
      const long col = n0 + wn * 64 + nI * 16 + fr;
      const float mb = -1e10f * (1.f - (float)amask[b * NS + col]);
#pragma unroll
      for (int r = 0; r < 4; ++r) {
        const long row = m0 + wm * 128 + mI * 16 + fq * 4 + r;
        eb[row * NS + col] = acc[mI][nI][r] + mb;
      }
    }
}

// ---- row softmax: a = bf16(exp(e - max)) (unnormalized), inv_sum = 1/sum
__global__ __launch_bounds__(256) void softmax_kernel(const float* __restrict__ e,
    short* __restrict__ a, float* __restrict__ inv_sum) {
  const long row = blockIdx.x;
  const int tid = threadIdx.x;
  __shared__ float red[4];
  f32x4 v = *(const f32x4*)(e + row * NS + tid * 4);
  float m = block_reduce_max(fmaxf(fmaxf(v[0], v[1]), fmaxf(v[2], v[3])), red);
  float p0 = expf(v[0] - m), p1 = expf(v[1] - m);
  float p2 = expf(v[2] - m), p3 = expf(v[3] - m);
  float s = block_reduce_sum(p0 + p1 + p2 + p3, red);
  s16x4 o = { f2bf(p0), f2bf(p1), f2bf(p2), f2bf(p3) };
  *(s16x4*)(a + row * NS + tid * 4) = o;
  if (tid == 0) inv_sum[row] = 1.f / s;
}

// ---- hidden = (a @ v) * inv_sum + normed   (f32, into d_out)
__global__ __launch_bounds__(512, 2) void av_kernel(const short* __restrict__ a,
    const short* __restrict__ vT, const float* __restrict__ inv_sum,
    const short* __restrict__ normed, float* __restrict__ hid) {
  const int b = blockIdx.z;
  const short* gA = a + (long)b * NS * NS;
  const short* gB = vT + (long)b * NH * NS;
  const long m0 = (long)blockIdx.x * 256;
  const long n0 = (long)blockIdx.y * 256;
  GEMM_MAIN();
#pragma unroll
  for (int mI = 0; mI < 8; ++mI)
#pragma unroll
    for (int nI = 0; nI < 4; ++nI) {
      const long col = n0 + wn * 64 + nI * 16 + fr;
#pragma unroll
      for (int r = 0; r < 4; ++r) {
        const long row = m0 + wm * 128 + mI * 16 + fq * 4 + r;
        const long gi = ((long)b * NS + row) * NH + col;
        hid[gi] = acc[mI][nI][r] * inv_sum[b * NS + row] + bf2f(normed[gi]);
      }
    }
}

// ---- pred[b,s] = hidden[b,s,:] . Wo + bo
__global__ __launch_bounds__(256) void pred_kernel(const float* __restrict__ hid,
    const float* __restrict__ Wo, const float* __restrict__ bo, float* __restrict__ pred) {
  const int row = blockIdx.x * 4 + (threadIdx.x >> 6);
  const int lane = threadIdx.x & 63;
  const float* hr = hid + (long)row * NH;
  float s = 0.f;
#pragma unroll
  for (int i = 0; i < 4; ++i) {
    f32x4 hv = *(const f32x4*)(hr + i * 256 + lane * 4);
    f32x4 wv = *(const f32x4*)(Wo + i * 256 + lane * 4);
    s += hv[0] * wv[0] + hv[1] * wv[1] + hv[2] * wv[2] + hv[3] * wv[3];
  }
  s = wave_reduce_sum(s);
  if (lane == 0) pred[row] = s + bo[0];
}

extern "C" void kernel_launch(void* const* d_in, const int* in_sizes, int n_in,
                              void* d_out, int out_size, void* d_ws, size_t ws_size,
                              hipStream_t stream) {
  (void)in_sizes; (void)n_in; (void)out_size; (void)ws_size;
  const int*   relation = (const int*)d_in[0];
  const float* x        = (const float*)d_in[1];
  const int*   sub_head = (const int*)d_in[2];
  const int*   sub_tail = (const int*)d_in[3];
  const int*   amask    = (const int*)d_in[4];
  const float* rel_emb  = (const float*)d_in[5];
  const float* Wrf      = (const float*)d_in[6];
  const float* brf      = (const float*)d_in[7];
  const float* cln_w    = (const float*)d_in[8];
  const float* cln_b    = (const float*)d_in[9];
  const float* Wwd      = (const float*)d_in[10];
  const float* Wbd      = (const float*)d_in[11];
  const float* Wq       = (const float*)d_in[12];
  const float* bq       = (const float*)d_in[13];
  const float* Wk       = (const float*)d_in[14];
  const float* bk       = (const float*)d_in[15];
  const float* Wv       = (const float*)d_in[16];
  const float* bv       = (const float*)d_in[17];
  const float* Wo       = (const float*)d_in[18];
  const float* bo       = (const float*)d_in[19];

  char* ws = (char*)d_ws;
  short* wq_bf = (short*)ws;                 // 1M shorts
  short* wk_bf = wq_bf + 1048576;
  short* wv_bf = wk_bf + 1048576;
  float* cond    = (float*)(ws + 6291456);   // [32, 2048]
  float* wln     = cond + 32 * 2048;         // [32, 1024]
  float* bln     = wln + 32 * 1024;          // [32, 1024]
  float* inv_sum = bln + 32 * 1024;          // [32768]
  short* normed  = (short*)(inv_sum + 32768);        // 33.5M bf16
  short* qb      = normed + 33554432;                // q, later reused as 'a'
  short* kb      = qb + 33554432;
  short* vT      = kb + 33554432;                    // transposed v
  float* e       = (float*)(vT + 33554432);          // 33.5M f32

  float* pred = (float*)d_out;
  float* hid  = pred + 32768;

  cvtw_kernel<<<3072, 256, 0, stream>>>(Wq, Wk, Wv, wq_bf);
  cond_kernel<<<dim3(NB, 16), 256, 0, stream>>>(relation, x, sub_head, sub_tail,
                                                rel_emb, Wrf, brf, cond);
  wb_kernel<<<NH, 256, 0, stream>>>(cond, Wwd, Wbd, cln_w, cln_b, wln, bln);
  ln_kernel<<<NB * NS, 256, 0, stream>>>(x, wln, bln, normed);
  qkv_kernel<<<dim3(128, 4, 3), 512, 0, stream>>>(normed, wq_bf, wk_bf, wv_bf,
                                                  bq, bk, bv, qb, kb, vT);
  escore_kernel<<<dim3(4, 4, 32), 512, 0, stream>>>(qb, kb, amask, e);
  softmax_kernel<<<NB * NS, 256, 0, stream>>>(e, qb, inv_sum);
  av_kernel<<<dim3(4, 4, 32), 512, 0, stream>>>(qb, vT, inv_sum, normed, hid);
  pred_kernel<<<NB * NS / 4, 256, 0, stream>>>(hid, Wo, bo, pred);
}

// Round 5
// 535.210 us; speedup vs baseline: 4.3994x; 1.0872x over previous
//
#include <hip/hip_runtime.h>
#include <hip/hip_bf16.h>

#define NB 32
#define NS 1024
#define NH 1024

typedef short s16x4 __attribute__((ext_vector_type(4)));
typedef short s16x8 __attribute__((ext_vector_type(8)));
typedef float f32x4 __attribute__((ext_vector_type(4)));

typedef __attribute__((address_space(3))) void lds_void;
typedef const __attribute__((address_space(1))) void gmem_void;

__device__ __forceinline__ short f2bf(float f) {
  __hip_bfloat16 h = __float2bfloat16(f);
  return *reinterpret_cast<short*>(&h);
}
__device__ __forceinline__ float bf2f(short s) {
  union { unsigned u; float f; } cv;
  cv.u = ((unsigned)(unsigned short)s) << 16;
  return cv.f;
}

__device__ __forceinline__ float wave_reduce_sum(float v) {
#pragma unroll
  for (int o = 32; o; o >>= 1) v += __shfl_xor(v, o);
  return v;
}
__device__ __forceinline__ float wave_reduce_max(float v) {
#pragma unroll
  for (int o = 32; o; o >>= 1) v = fmaxf(v, __shfl_xor(v, o));
  return v;
}
__device__ __forceinline__ float block_reduce_sum(float v, float* red) {
  v = wave_reduce_sum(v);
  __syncthreads();
  if ((threadIdx.x & 63) == 0) red[threadIdx.x >> 6] = v;
  __syncthreads();
  return red[0] + red[1] + red[2] + red[3];
}
__device__ __forceinline__ float block_reduce_max(float v, float* red) {
  v = wave_reduce_max(v);
  __syncthreads();
  if ((threadIdx.x & 63) == 0) red[threadIdx.x >> 6] = v;
  __syncthreads();
  return fmaxf(fmaxf(red[0], red[1]), fmaxf(red[2], red[3]));
}

// ==================== 256x256 8-phase bf16 GEMM core ====================
// C = A[M,1024] * B[N,1024]^T. 512 threads = 8 waves (2M x 4N).
// Per wave: 128x64 output = acc[8][4] (16x16 frags). BK=64, 2 K-tiles/iter,
// double-buffered LDS (128 KiB), st-swizzled (col8 ^= row&7) on both the
// global_load_lds SOURCE and the ds_read address (rule #21 involution).
// Caller declares `lds` (>= 65536 shorts) before GEMM_MAIN().

#define BAR1 do { __builtin_amdgcn_s_barrier();                              \
                  asm volatile("s_waitcnt lgkmcnt(0)" ::: "memory");         \
                  __builtin_amdgcn_sched_barrier(0); } while (0)
#define BAR2 do { __builtin_amdgcn_s_barrier();                              \
                  asm volatile("" ::: "memory"); } while (0)
#define VW   asm volatile("s_waitcnt vmcnt(4)" ::: "memory")

#define GEMM_PRE()                                                           \
  const int tid  = threadIdx.x;                                              \
  const int lane = tid & 63;                                                 \
  const int w    = tid >> 6;                                                 \
  const int wm   = w >> 2, wn = w & 3;                                       \
  const int fr   = lane & 15, fq = lane >> 4;                                \
  /* per-thread stage source offset: row(tid>>3)*K + swizzled col */         \
  const long tA  = (long)(tid >> 3) * 1024 +                                 \
                   (((tid & 7) ^ ((tid >> 3) & 7)) << 3);                    \
  /* swizzled k-col byte offsets for ds_read (elements) */                   \
  const int kc0  = (fq * 8) ^ ((fr & 7) * 8);                                \
  const int kc1  = (fq * 8 + 32) ^ ((fr & 7) * 8);                           \
  const int rdA  = wm * 8192 + fr * 64;                                      \
  const int rdB  = 16384 + (wn >> 1) * 8192 + (wn & 1) * 4096 + fr * 64;     \
  const int wsl  = w * 512;                                                  \
  f32x4 acc[8][4];                                                           \
  s16x8 aF[4][2], bF[2][2][2];                                               \
  _Pragma("unroll") for (int i_ = 0; i_ < 8; ++i_)                           \
    _Pragma("unroll") for (int j_ = 0; j_ < 4; ++j_)                         \
      acc[i_][j_] = (f32x4){0.f, 0.f, 0.f, 0.f};

// stage one 128x64 half-tile (2 x global_load_lds of 8KB rounds)
#define STAGE(d, isB, h, kt)                                                 \
  do {                                                                       \
    const short* _g = ((isB) ? gB + (n0 + (h) * 128) * 1024                  \
                             : gA + (m0 + (h) * 128) * 1024) +               \
                      (long)((kt) & 15) * 64 + tA;                           \
    short* _l = lds + (d) * 32768 + (isB) * 16384 + (h) * 8192 + wsl;        \
    __builtin_amdgcn_global_load_lds((gmem_void*)_g, (lds_void*)_l,          \
                                     16, 0, 0);                              \
    __builtin_amdgcn_global_load_lds((gmem_void*)(_g + 65536),               \
                                     (lds_void*)(_l + 4096), 16, 0, 0);      \
  } while (0)

#define RD_A(d, mq)                                                          \
  _Pragma("unroll") for (int mi = 0; mi < 4; ++mi) {                         \
    aF[mi][0] = *(const s16x8*)(lds + (d) * 32768 + rdA + (mq) * 4096 +      \
                                mi * 1024 + kc0);                            \
    aF[mi][1] = *(const s16x8*)(lds + (d) * 32768 + rdA + (mq) * 4096 +      \
                                mi * 1024 + kc1);                            \
  }
#define RD_B(d, nq)                                                          \
  _Pragma("unroll") for (int ni = 0; ni < 2; ++ni) {                         \
    bF[nq][ni][0] = *(const s16x8*)(lds + (d) * 32768 + rdB + (nq) * 2048 +  \
                                    ni * 1024 + kc0);                        \
    bF[nq][ni][1] = *(const s16x8*)(lds + (d) * 32768 + rdB + (nq) * 2048 +  \
                                    ni * 1024 + kc1);                        \
  }
#define MMA(mq, nq)                                                          \
  do {                                                                       \
    __builtin_amdgcn_s_setprio(1);                                           \
    _Pragma("unroll") for (int kk = 0; kk < 2; ++kk)                         \
      _Pragma("unroll") for (int mi = 0; mi < 4; ++mi)                       \
        _Pragma("unroll") for (int ni = 0; ni < 2; ++ni)                     \
          acc[(mq) * 4 + mi][(nq) * 2 + ni] =                                \
              __builtin_amdgcn_mfma_f32_16x16x32_bf16(                       \
                  aF[mi][kk], bF[nq][ni][kk],                                \
                  acc[(mq) * 4 + mi][(nq) * 2 + ni], 0, 0, 0);               \
    __builtin_amdgcn_s_setprio(0);                                           \
  } while (0)

// prologue: tile0 full + tile1 B-halves (12 loads), wait oldest 8 (tile0)
// steady iter i: consume 2i (dbuf0, ph1-4), 2i+1 (dbuf1, ph5-8)
// vmcnt(4)@ph4: d1 tile landed, ph3,4 in flight
// vmcnt(4)@ph8: d0 tile landed, ph7,8 in flight
#define GEMM_MAIN()                                                          \
  GEMM_PRE();                                                                \
  STAGE(0, 1, 0, 0); STAGE(0, 1, 1, 0); STAGE(0, 0, 0, 0); STAGE(0, 0, 1, 0);\
  STAGE(1, 1, 0, 1); STAGE(1, 1, 1, 1);                                      \
  VW; BAR2;                                                                  \
  for (int it = 0; it < 8; ++it) {                                           \
    const int t1 = 2 * it + 1, t2 = 2 * it + 2, t3 = 2 * it + 3;             \
    RD_A(0, 0); RD_B(0, 0); STAGE(1, 0, 0, t1); BAR1; MMA(0, 0); BAR2;       \
    RD_B(0, 1);             STAGE(1, 0, 1, t1); BAR1; MMA(0, 1); BAR2;       \
    RD_A(0, 1);             STAGE(0, 1, 0, t2); BAR1; MMA(1, 1); BAR2;       \
                            STAGE(0, 1, 1, t2); BAR1; MMA(1, 0); VW; BAR2;   \
    RD_A(1, 0); RD_B(1, 0); STAGE(0, 0, 0, t2); BAR1; MMA(0, 0); BAR2;       \
    RD_B(1, 1);             STAGE(0, 0, 1, t2); BAR1; MMA(0, 1); BAR2;       \
    RD_A(1, 1);             STAGE(1, 1, 0, t3); BAR1; MMA(1, 1); BAR2;       \
                            STAGE(1, 1, 1, t3); BAR1; MMA(1, 0); VW; BAR2;   \
  }

// epilogue index map: row = m0 + wm*128 + mI*16 + fq*4 + r
//                     col = n0 + wn*64  + nI*16 + fr

// ---- weights f32 -> bf16 (Wq,Wk,Wv concatenated -> [3072][1024])
__global__ __launch_bounds__(256) void cvtw_kernel(const float* __restrict__ Wq,
    const float* __restrict__ Wk, const float* __restrict__ Wv, short* __restrict__ out) {
  long i = ((long)blockIdx.x * 256 + threadIdx.x) * 4;
  int seg = (int)(i >> 20);
  long off = i & 1048575;
  const float* src = seg == 0 ? Wq : (seg == 1 ? Wk : Wv);
  f32x4 v = *(const f32x4*)(src + off);
  s16x4 o = { f2bf(v[0]), f2bf(v[1]), f2bf(v[2]), f2bf(v[3]) };
  *(s16x4*)(out + i) = o;
}

// ---- cond = [relu6(rel_emb[rel] @ Wrf^T + brf), 0.5*(x[sh]+x[st])]   [B, 2H]
__global__ __launch_bounds__(256) void cond_kernel(const int* __restrict__ relation,
    const float* __restrict__ x, const int* __restrict__ sub_head,
    const int* __restrict__ sub_tail, const float* __restrict__ rel_emb,
    const float* __restrict__ Wrf, const float* __restrict__ brf, float* __restrict__ cond) {
  const int b = blockIdx.x;
  const int gc = blockIdx.y;
  const int tid = threadIdx.x;
  __shared__ float r[NH];
  const int rid = relation[b];
  for (int h = tid * 4; h < NH; h += 1024)
    *(f32x4*)(r + h) = *(const f32x4*)(rel_emb + (long)rid * NH + h);
  if (gc == 0) {
    const int sh = sub_head[b], st = sub_tail[b];
    for (int h = tid * 4; h < NH; h += 1024) {
      f32x4 a = *(const f32x4*)(x + ((long)b * NS + sh) * NH + h);
      f32x4 c = *(const f32x4*)(x + ((long)b * NS + st) * NH + h);
      f32x4 o = { 0.5f * (a[0] + c[0]), 0.5f * (a[1] + c[1]),
                  0.5f * (a[2] + c[2]), 0.5f * (a[3] + c[3]) };
      *(f32x4*)(cond + b * 2 * NH + NH + h) = o;
    }
  }
  __syncthreads();
  const int lane = tid & 63, wid = tid >> 6;
#pragma unroll
  for (int gi = 0; gi < 16; ++gi) {
    const int g = gc * 64 + wid * 16 + gi;
    float s = 0.f;
#pragma unroll
    for (int h = lane * 4; h < NH; h += 256) {
      f32x4 wv = *(const f32x4*)(Wrf + (long)g * NH + h);
      f32x4 rv = *(const f32x4*)(r + h);
      s += wv[0] * rv[0] + wv[1] * rv[1] + wv[2] * rv[2] + wv[3] * rv[3];
    }
    s = wave_reduce_sum(s);
    if (lane == 0) cond[b * 2 * NH + g] = fminf(fmaxf(s + brf[g], 0.f), 6.f);
  }
}

// ---- wln/bln[b,g] = cond[b,:] . W{wd,bd}[g,:] + cln_{w,b}[g]
__global__ __launch_bounds__(256) void wb_kernel(const float* __restrict__ cond,
    const float* __restrict__ Wwd, const float* __restrict__ Wbd,
    const float* __restrict__ cln_w, const float* __restrict__ cln_b,
    float* __restrict__ wln, float* __restrict__ bln) {
  const int g = blockIdx.x;
  const int tid = threadIdx.x;
  __shared__ float wrow[2 * NH];
  __shared__ float brow[2 * NH];
  for (int i = tid * 4; i < 2 * NH; i += 1024) {
    *(f32x4*)(wrow + i) = *(const f32x4*)(Wwd + (long)g * 2 * NH + i);
    *(f32x4*)(brow + i) = *(const f32x4*)(Wbd + (long)g * 2 * NH + i);
  }
  __syncthreads();
  const int lane = tid & 63, wid = tid >> 6;
  const float cw = cln_w[g], cb = cln_b[g];
  for (int b = wid; b < NB; b += 4) {
    float sw = 0.f, sb = 0.f;
#pragma unroll
    for (int c = lane * 4; c < 2 * NH; c += 256) {
      f32x4 cv = *(const f32x4*)(cond + b * 2 * NH + c);
      f32x4 wv = *(const f32x4*)(wrow + c);
      f32x4 bv = *(const f32x4*)(brow + c);
      sw += cv[0] * wv[0] + cv[1] * wv[1] + cv[2] * wv[2] + cv[3] * wv[3];
      sb += cv[0] * bv[0] + cv[1] * bv[1] + cv[2] * bv[2] + cv[3] * bv[3];
    }
    sw = wave_reduce_sum(sw);
    sb = wave_reduce_sum(sb);
    if (lane == 0) {
      wln[b * NH + g] = sw + cw;
      bln[b * NH + g] = sb + cb;
    }
  }
}

// ---- conditional LayerNorm -> normed (bf16)
__global__ __launch_bounds__(256) void ln_kernel(const float* __restrict__ x,
    const float* __restrict__ wln, const float* __restrict__ bln, short* __restrict__ normed) {
  const long row = blockIdx.x;
  const int tid = threadIdx.x;
  const long b = row >> 10;
  __shared__ float red[4];
  f32x4 v = *(const f32x4*)(x + row * NH + tid * 4);
  float mean = block_reduce_sum(v[0] + v[1] + v[2] + v[3], red) * (1.f / NH);
  float c0 = v[0] - mean, c1 = v[1] - mean, c2 = v[2] - mean, c3 = v[3] - mean;
  float var = block_reduce_sum(c0 * c0 + c1 * c1 + c2 * c2 + c3 * c3, red) * (1.f / NH);
  float rstd = rsqrtf(var + 1e-12f);
  f32x4 wv = *(const f32x4*)(wln + b * NH + tid * 4);
  f32x4 bv = *(const f32x4*)(bln + b * NH + tid * 4);
  s16x4 o = { f2bf(c0 * rstd * wv[0] + bv[0]), f2bf(c1 * rstd * wv[1] + bv[1]),
              f2bf(c2 * rstd * wv[2] + bv[2]), f2bf(c3 * rstd * wv[3] + bv[3]) };
  *(s16x4*)(normed + row * NH + tid * 4) = o;
}

// ---- fused qkv GEMM: grid (12, 128), x = n-fast (A-tile shared by 12
// consecutive blocks -> L2/L3 resident staging). z = x>>2 selects q/k/v.
// v is transposed via LDS ([256 h][264-pad t]) for coalesced vT stores.
__global__ __launch_bounds__(512, 2) void qkv_kernel(const short* __restrict__ A,
    const short* __restrict__ Wqkv,
    const float* __restrict__ bq, const float* __restrict__ bk, const float* __restrict__ bv,
    short* __restrict__ q, short* __restrict__ k, short* __restrict__ vT) {
  __shared__ short lds[67584];  // 135168 B: 128K staging, reused for vT transpose
  const short* gA = A;
  const short* gB = Wqkv;
  const long n0 = (long)blockIdx.x * 256;   // row in 3072-row concat weight
  const long m0 = (long)blockIdx.y * 256;
  GEMM_MAIN();
  const int z = blockIdx.x >> 2;
  const long hc0 = (long)(blockIdx.x & 3) * 256;  // col within H
  const float* bias = z == 0 ? bq : (z == 1 ? bk : bv);
  if (z < 2) {
    short* dst = z == 0 ? q : k;
#pragma unroll
    for (int nI = 0; nI < 4; ++nI) {
      const long col = hc0 + wn * 64 + nI * 16 + fr;
      const float bcol = bias[col];
#pragma unroll
      for (int mI = 0; mI < 8; ++mI)
#pragma unroll
        for (int r = 0; r < 4; ++r) {
          const long row = m0 + wm * 128 + mI * 16 + fq * 4 + r;
          dst[row * NH + col] = f2bf(fmaxf(acc[mI][nI][r] + bcol, 0.f));
        }
    }
  } else {
    // drain stray wrap-around stages, then reuse LDS for the transpose
    asm volatile("s_waitcnt vmcnt(0)" ::: "memory");
    __syncthreads();
#pragma unroll
    for (int nI = 0; nI < 4; ++nI) {
      const int hl = wn * 64 + nI * 16 + fr;
      const float bcol = bias[hc0 + hl];
#pragma unroll
      for (int mI = 0; mI < 8; ++mI) {
        const int tl = wm * 128 + mI * 16 + fq * 4;
        s16x4 pk = { f2bf(fmaxf(acc[mI][nI][0] + bcol, 0.f)),
                     f2bf(fmaxf(acc[mI][nI][1] + bcol, 0.f)),
                     f2bf(fmaxf(acc[mI][nI][2] + bcol, 0.f)),
                     f2bf(fmaxf(acc[mI][nI][3] + bcol, 0.f)) };
        *(s16x4*)(lds + hl * 264 + tl) = pk;
      }
    }
    __syncthreads();
    const int h = tid >> 1, half = tid & 1;
    const long bb = m0 >> 10;
    short* dst = vT + ((bb * NH) + hc0 + h) * NS + (m0 & 1023) + half * 128;
    const short* src = lds + h * 264 + half * 128;
#pragma unroll
    for (int j = 0; j < 16; ++j)
      *(s16x8*)(dst + j * 8) = *(const s16x8*)(src + j * 8);
  }
}

// ---- e[b,s,t] = q[b,s,:] . k[b,t,:] - 1e10*(1-mask[b,t])   (f32)
__global__ __launch_bounds__(512, 2) void escore_kernel(const short* __restrict__ q,
    const short* __restrict__ k, const int* __restrict__ amask, float* __restrict__ e) {
  __shared__ short lds[65536];
  const int b = blockIdx.z;
  const short* gA = q + (long)b * NS * NH;
  const short* gB = k + (long)b * NS * NH;
  const long m0 = (long)blockIdx.x * 256;
  const long n0 = (long)blockIdx.y * 256;
  GEMM_MAIN();
  float* eb = e + (long)b * NS * NS;
#pragma unroll
  for (int mI = 0; mI < 8; ++mI)
#pragma unroll
    for (int nI = 0; nI < 4; ++nI) {
      const long col = n0 + wn * 64 + nI * 16 + fr;
      const float mb = -1e10f * (1.f - (float)amask[b * NS + col]);
#pragma unroll
      for (int r = 0; r < 4; ++r) {
        const long row = m0 + wm * 128 + mI * 16 + fq * 4 + r;
        eb[row * NS + col] = acc[mI][nI][r] + mb;
      }
    }
}

// ---- row softmax: a = bf16(exp(e - max)) (unnormalized), inv_sum = 1/sum
__global__ __launch_bounds__(256) void softmax_kernel(const float* __restrict__ e,
    short* __restrict__ a, float* __restrict__ inv_sum) {
  const long row = blockIdx.x;
  const int tid = threadIdx.x;
  __shared__ float red[4];
  f32x4 v = *(const f32x4*)(e + row * NS + tid * 4);
  float m = block_reduce_max(fmaxf(fmaxf(v[0], v[1]), fmaxf(v[2], v[3])), red);
  float p0 = expf(v[0] - m), p1 = expf(v[1] - m);
  float p2 = expf(v[2] - m), p3 = expf(v[3] - m);
  float s = block_reduce_sum(p0 + p1 + p2 + p3, red);
  s16x4 o = { f2bf(p0), f2bf(p1), f2bf(p2), f2bf(p3) };
  *(s16x4*)(a + row * NS + tid * 4) = o;
  if (tid == 0) inv_sum[row] = 1.f / s;
}

// ---- hidden = (a @ v) * inv_sum + normed (f32, into d_out)
//      + fused pred partials, one slice PER WAVE-COLUMN (wn) to avoid the
//      round-4 race: slice = blockIdx.y*4 + wn, 16 slices total.
__global__ __launch_bounds__(512, 2) void av_kernel(const short* __restrict__ a,
    const short* __restrict__ vT, const float* __restrict__ inv_sum,
    const short* __restrict__ normed, const float* __restrict__ Wo,
    float* __restrict__ hid, float* __restrict__ pred_part) {
  __shared__ short lds[65536];
  const int b = blockIdx.z;
  const short* gA = a + (long)b * NS * NS;
  const short* gB = vT + (long)b * NH * NS;
  const long m0 = (long)blockIdx.x * 256;
  const long n0 = (long)blockIdx.y * 256;
  GEMM_MAIN();
  float pp[8][4];
#pragma unroll
  for (int mI = 0; mI < 8; ++mI)
#pragma unroll
    for (int r = 0; r < 4; ++r) pp[mI][r] = 0.f;
#pragma unroll
  for (int nI = 0; nI < 4; ++nI) {
    const long col = n0 + wn * 64 + nI * 16 + fr;
    const float wo = Wo[col];
#pragma unroll
    for (int mI = 0; mI < 8; ++mI)
#pragma unroll
      for (int r = 0; r < 4; ++r) {
        const long row = m0 + wm * 128 + mI * 16 + fq * 4 + r;
        const long gi = ((long)b * NS + row) * NH + col;
        float hv = acc[mI][nI][r] * inv_sum[b * NS + row] + bf2f(normed[gi]);
        hid[gi] = hv;
        pp[mI][r] += hv * wo;
      }
  }
#pragma unroll
  for (int mI = 0; mI < 8; ++mI)
#pragma unroll
    for (int r = 0; r < 4; ++r) {
      float v = pp[mI][r];
      v += __shfl_xor(v, 1);
      v += __shfl_xor(v, 2);
      v += __shfl_xor(v, 4);
      v += __shfl_xor(v, 8);
      if (fr == 0)
        pred_part[((long)blockIdx.y * 4 + wn) * (NB * NS) + (long)b * NS + m0 +
                  wm * 128 + mI * 16 + fq * 4 + r] = v;
    }
}

// ---- pred[row] = sum of 16 partials + bo
__global__ __launch_bounds__(256) void pred_finish_kernel(const float* __restrict__ pp,
    const float* __restrict__ bo, float* __restrict__ pred) {
  const int i = (blockIdx.x * 256 + threadIdx.x) * 4;
  const float bz = bo[0];
  f32x4 o = { bz, bz, bz, bz };
#pragma unroll
  for (int j = 0; j < 16; ++j) {
    f32x4 a = *(const f32x4*)(pp + (long)j * (NB * NS) + i);
    o[0] += a[0]; o[1] += a[1]; o[2] += a[2]; o[3] += a[3];
  }
  *(f32x4*)(pred + i) = o;
}

extern "C" void kernel_launch(void* const* d_in, const int* in_sizes, int n_in,
                              void* d_out, int out_size, void* d_ws, size_t ws_size,
                              hipStream_t stream) {
  (void)in_sizes; (void)n_in; (void)out_size; (void)ws_size;
  const int*   relation = (const int*)d_in[0];
  const float* x        = (const float*)d_in[1];
  const int*   sub_head = (const int*)d_in[2];
  const int*   sub_tail = (const int*)d_in[3];
  const int*   amask    = (const int*)d_in[4];
  const float* rel_emb  = (const float*)d_in[5];
  const float* Wrf      = (const float*)d_in[6];
  const float* brf      = (const float*)d_in[7];
  const float* cln_w    = (const float*)d_in[8];
  const float* cln_b    = (const float*)d_in[9];
  const float* Wwd      = (const float*)d_in[10];
  const float* Wbd      = (const float*)d_in[11];
  const float* Wq       = (const float*)d_in[12];
  const float* bq       = (const float*)d_in[13];
  const float* Wk       = (const float*)d_in[14];
  const float* bk       = (const float*)d_in[15];
  const float* Wv       = (const float*)d_in[16];
  const float* bv       = (const float*)d_in[17];
  const float* Wo       = (const float*)d_in[18];
  const float* bo       = (const float*)d_in[19];

  char* ws = (char*)d_ws;
  short* wqkv_bf = (short*)ws;               // 3M shorts [3072][1024]
  float* cond    = (float*)(ws + 6291456);   // [32, 2048]
  float* wln     = cond + 32 * 2048;         // [32, 1024]
  float* bln     = wln + 32 * 1024;          // [32, 1024]
  float* inv_sum = bln + 32 * 1024;          // [32768]
  short* normed  = (short*)(inv_sum + 32768);        // 33.5M bf16
  short* qb      = normed + 33554432;                // q, later reused as 'a'
  short* kb      = qb + 33554432;
  short* vT      = kb + 33554432;                    // transposed v
  float* e       = (float*)(vT + 33554432);          // 33.5M f32
  float* pred_part = e + 33554432;                   // [16][32768] f32

  float* pred = (float*)d_out;
  float* hid  = pred + 32768;

  cvtw_kernel<<<3072, 256, 0, stream>>>(Wq, Wk, Wv, wqkv_bf);
  cond_kernel<<<dim3(NB, 16), 256, 0, stream>>>(relation, x, sub_head, sub_tail,
                                                rel_emb, Wrf, brf, cond);
  wb_kernel<<<NH, 256, 0, stream>>>(cond, Wwd, Wbd, cln_w, cln_b, wln, bln);
  ln_kernel<<<NB * NS, 256, 0, stream>>>(x, wln, bln, normed);
  qkv_kernel<<<dim3(12, 128), 512, 0, stream>>>(normed, wqkv_bf,
                                                bq, bk, bv, qb, kb, vT);
  escore_kernel<<<dim3(4, 4, 32), 512, 0, stream>>>(qb, kb, amask, e);
  softmax_kernel<<<NB * NS, 256, 0, stream>>>(e, qb, inv_sum);
  av_kernel<<<dim3(4, 4, 32), 512, 0, stream>>>(qb, vT, inv_sum, normed, Wo,
                                                hid, pred_part);
  pred_finish_kernel<<<32, 256, 0, stream>>>(pred_part, bo, pred);
}

// Round 6
// 534.293 us; speedup vs baseline: 4.4070x; 1.0017x over previous
//
#include <hip/hip_runtime.h>
#include <hip/hip_bf16.h>

#define NB 32
#define NS 1024
#define NH 1024

typedef short s16x4 __attribute__((ext_vector_type(4)));
typedef short s16x8 __attribute__((ext_vector_type(8)));
typedef float f32x4 __attribute__((ext_vector_type(4)));

typedef __attribute__((address_space(3))) void lds_void;
typedef const __attribute__((address_space(1))) void gmem_void;

__device__ __forceinline__ short f2bf(float f) {
  __hip_bfloat16 h = __float2bfloat16(f);
  return *reinterpret_cast<short*>(&h);
}
__device__ __forceinline__ float bf2f(short s) {
  union { unsigned u; float f; } cv;
  cv.u = ((unsigned)(unsigned short)s) << 16;
  return cv.f;
}

__device__ __forceinline__ float wave_reduce_sum(float v) {
#pragma unroll
  for (int o = 32; o; o >>= 1) v += __shfl_xor(v, o);
  return v;
}
__device__ __forceinline__ float wave_reduce_max(float v) {
#pragma unroll
  for (int o = 32; o; o >>= 1) v = fmaxf(v, __shfl_xor(v, o));
  return v;
}
__device__ __forceinline__ float block_reduce_sum(float v, float* red) {
  v = wave_reduce_sum(v);
  __syncthreads();
  if ((threadIdx.x & 63) == 0) red[threadIdx.x >> 6] = v;
  __syncthreads();
  return red[0] + red[1] + red[2] + red[3];
}
__device__ __forceinline__ float block_reduce_max(float v, float* red) {
  v = wave_reduce_max(v);
  __syncthreads();
  if ((threadIdx.x & 63) == 0) red[threadIdx.x >> 6] = v;
  __syncthreads();
  return fmaxf(fmaxf(red[0], red[1]), fmaxf(red[2], red[3]));
}

// ==================== 256x256 8-phase bf16 GEMM core ====================
// C = A[M,1024] * B[N,1024]^T. 512 threads = 8 waves (2M x 4N).
// Per wave: 128x64 output = acc[8][4] (16x16 frags). BK=64, 2 K-tiles/iter,
// double-buffered LDS (128 KiB), st-swizzled (col8 ^= row&7) on both the
// global_load_lds SOURCE and the ds_read address (rule #21 involution).
// Caller declares `lds` (>= 65536 shorts) before GEMM_MAIN().

#define BAR1 do { __builtin_amdgcn_s_barrier();                              \
                  asm volatile("s_waitcnt lgkmcnt(0)" ::: "memory");         \
                  __builtin_amdgcn_sched_barrier(0); } while (0)
#define BAR2 do { __builtin_amdgcn_s_barrier();                              \
                  asm volatile("" ::: "memory"); } while (0)
#define VW   asm volatile("s_waitcnt vmcnt(4)" ::: "memory")

#define GEMM_PRE()                                                           \
  const int tid  = threadIdx.x;                                              \
  const int lane = tid & 63;                                                 \
  const int w    = tid >> 6;                                                 \
  const int wm   = w >> 2, wn = w & 3;                                       \
  const int fr   = lane & 15, fq = lane >> 4;                                \
  /* per-thread stage source offset: row(tid>>3)*K + swizzled col */         \
  const long tA  = (long)(tid >> 3) * 1024 +                                 \
                   (((tid & 7) ^ ((tid >> 3) & 7)) << 3);                    \
  /* swizzled k-col byte offsets for ds_read (elements) */                   \
  const int kc0  = (fq * 8) ^ ((fr & 7) * 8);                                \
  const int kc1  = (fq * 8 + 32) ^ ((fr & 7) * 8);                           \
  const int rdA  = wm * 8192 + fr * 64;                                      \
  const int rdB  = 16384 + (wn >> 1) * 8192 + (wn & 1) * 4096 + fr * 64;     \
  const int wsl  = w * 512;                                                  \
  f32x4 acc[8][4];                                                           \
  s16x8 aF[4][2], bF[2][2][2];                                               \
  _Pragma("unroll") for (int i_ = 0; i_ < 8; ++i_)                           \
    _Pragma("unroll") for (int j_ = 0; j_ < 4; ++j_)                         \
      acc[i_][j_] = (f32x4){0.f, 0.f, 0.f, 0.f};

// stage one 128x64 half-tile (2 x global_load_lds of 8KB rounds)
#define STAGE(d, isB, h, kt)                                                 \
  do {                                                                       \
    const short* _g = ((isB) ? gB + (n0 + (h) * 128) * 1024                  \
                             : gA + (m0 + (h) * 128) * 1024) +               \
                      (long)((kt) & 15) * 64 + tA;                           \
    short* _l = lds + (d) * 32768 + (isB) * 16384 + (h) * 8192 + wsl;        \
    __builtin_amdgcn_global_load_lds((gmem_void*)_g, (lds_void*)_l,          \
                                     16, 0, 0);                              \
    __builtin_amdgcn_global_load_lds((gmem_void*)(_g + 65536),               \
                                     (lds_void*)(_l + 4096), 16, 0, 0);      \
  } while (0)

#define RD_A(d, mq)                                                          \
  _Pragma("unroll") for (int mi = 0; mi < 4; ++mi) {                         \
    aF[mi][0] = *(const s16x8*)(lds + (d) * 32768 + rdA + (mq) * 4096 +      \
                                mi * 1024 + kc0);                            \
    aF[mi][1] = *(const s16x8*)(lds + (d) * 32768 + rdA + (mq) * 4096 +      \
                                mi * 1024 + kc1);                            \
  }
#define RD_B(d, nq)                                                          \
  _Pragma("unroll") for (int ni = 0; ni < 2; ++ni) {                         \
    bF[nq][ni][0] = *(const s16x8*)(lds + (d) * 32768 + rdB + (nq) * 2048 +  \
                                    ni * 1024 + kc0);                        \
    bF[nq][ni][1] = *(const s16x8*)(lds + (d) * 32768 + rdB + (nq) * 2048 +  \
                                    ni * 1024 + kc1);                        \
  }
#define MMA(mq, nq)                                                          \
  do {                                                                       \
    __builtin_amdgcn_s_setprio(1);                                           \
    _Pragma("unroll") for (int kk = 0; kk < 2; ++kk)                         \
      _Pragma("unroll") for (int mi = 0; mi < 4; ++mi)                       \
        _Pragma("unroll") for (int ni = 0; ni < 2; ++ni)                     \
          acc[(mq) * 4 + mi][(nq) * 2 + ni] =                                \
              __builtin_amdgcn_mfma_f32_16x16x32_bf16(                       \
                  aF[mi][kk], bF[nq][ni][kk],                                \
                  acc[(mq) * 4 + mi][(nq) * 2 + ni], 0, 0, 0);               \
    __builtin_amdgcn_s_setprio(0);                                           \
  } while (0)

// prologue: tile0 full + tile1 B-halves (12 loads), wait oldest 8 (tile0)
// steady iter i: consume 2i (dbuf0, ph1-4), 2i+1 (dbuf1, ph5-8)
// vmcnt(4)@ph4: d1 tile landed, ph3,4 in flight
// vmcnt(4)@ph8: d0 tile landed, ph7,8 in flight
#define GEMM_MAIN()                                                          \
  GEMM_PRE();                                                                \
  STAGE(0, 1, 0, 0); STAGE(0, 1, 1, 0); STAGE(0, 0, 0, 0); STAGE(0, 0, 1, 0);\
  STAGE(1, 1, 0, 1); STAGE(1, 1, 1, 1);                                      \
  VW; BAR2;                                                                  \
  for (int it = 0; it < 8; ++it) {                                           \
    const int t1 = 2 * it + 1, t2 = 2 * it + 2, t3 = 2 * it + 3;             \
    RD_A(0, 0); RD_B(0, 0); STAGE(1, 0, 0, t1); BAR1; MMA(0, 0); BAR2;       \
    RD_B(0, 1);             STAGE(1, 0, 1, t1); BAR1; MMA(0, 1); BAR2;       \
    RD_A(0, 1);             STAGE(0, 1, 0, t2); BAR1; MMA(1, 1); BAR2;       \
                            STAGE(0, 1, 1, t2); BAR1; MMA(1, 0); VW; BAR2;   \
    RD_A(1, 0); RD_B(1, 0); STAGE(0, 0, 0, t2); BAR1; MMA(0, 0); BAR2;       \
    RD_B(1, 1);             STAGE(0, 0, 1, t2); BAR1; MMA(0, 1); BAR2;       \
    RD_A(1, 1);             STAGE(1, 1, 0, t3); BAR1; MMA(1, 1); BAR2;       \
                            STAGE(1, 1, 1, t3); BAR1; MMA(1, 0); VW; BAR2;   \
  }

// epilogue index map: row = m0 + wm*128 + mI*16 + fq*4 + r
//                     col = n0 + wn*64  + nI*16 + fr

// ---- weights f32 -> bf16 (Wq,Wk,Wv concatenated -> [3072][1024])
__global__ __launch_bounds__(256) void cvtw_kernel(const float* __restrict__ Wq,
    const float* __restrict__ Wk, const float* __restrict__ Wv, short* __restrict__ out) {
  long i = ((long)blockIdx.x * 256 + threadIdx.x) * 4;
  int seg = (int)(i >> 20);
  long off = i & 1048575;
  const float* src = seg == 0 ? Wq : (seg == 1 ? Wk : Wv);
  f32x4 v = *(const f32x4*)(src + off);
  s16x4 o = { f2bf(v[0]), f2bf(v[1]), f2bf(v[2]), f2bf(v[3]) };
  *(s16x4*)(out + i) = o;
}

// ---- cond = [relu6(rel_emb[rel] @ Wrf^T + brf), 0.5*(x[sh]+x[st])]   [B, 2H]
__global__ __launch_bounds__(256) void cond_kernel(const int* __restrict__ relation,
    const float* __restrict__ x, const int* __restrict__ sub_head,
    const int* __restrict__ sub_tail, const float* __restrict__ rel_emb,
    const float* __restrict__ Wrf, const float* __restrict__ brf, float* __restrict__ cond) {
  const int b = blockIdx.x;
  const int gc = blockIdx.y;
  const int tid = threadIdx.x;
  __shared__ float r[NH];
  const int rid = relation[b];
  for (int h = tid * 4; h < NH; h += 1024)
    *(f32x4*)(r + h) = *(const f32x4*)(rel_emb + (long)rid * NH + h);
  if (gc == 0) {
    const int sh = sub_head[b], st = sub_tail[b];
    for (int h = tid * 4; h < NH; h += 1024) {
      f32x4 a = *(const f32x4*)(x + ((long)b * NS + sh) * NH + h);
      f32x4 c = *(const f32x4*)(x + ((long)b * NS + st) * NH + h);
      f32x4 o = { 0.5f * (a[0] + c[0]), 0.5f * (a[1] + c[1]),
                  0.5f * (a[2] + c[2]), 0.5f * (a[3] + c[3]) };
      *(f32x4*)(cond + b * 2 * NH + NH + h) = o;
    }
  }
  __syncthreads();
  const int lane = tid & 63, wid = tid >> 6;
#pragma unroll
  for (int gi = 0; gi < 16; ++gi) {
    const int g = gc * 64 + wid * 16 + gi;
    float s = 0.f;
#pragma unroll
    for (int h = lane * 4; h < NH; h += 256) {
      f32x4 wv = *(const f32x4*)(Wrf + (long)g * NH + h);
      f32x4 rv = *(const f32x4*)(r + h);
      s += wv[0] * rv[0] + wv[1] * rv[1] + wv[2] * rv[2] + wv[3] * rv[3];
    }
    s = wave_reduce_sum(s);
    if (lane == 0) cond[b * 2 * NH + g] = fminf(fmaxf(s + brf[g], 0.f), 6.f);
  }
}

// ---- wln/bln[b,g] = cond[b,:] . W{wd,bd}[g,:] + cln_{w,b}[g]
__global__ __launch_bounds__(256) void wb_kernel(const float* __restrict__ cond,
    const float* __restrict__ Wwd, const float* __restrict__ Wbd,
    const float* __restrict__ cln_w, const float* __restrict__ cln_b,
    float* __restrict__ wln, float* __restrict__ bln) {
  const int g = blockIdx.x;
  const int tid = threadIdx.x;
  __shared__ float wrow[2 * NH];
  __shared__ float brow[2 * NH];
  for (int i = tid * 4; i < 2 * NH; i += 1024) {
    *(f32x4*)(wrow + i) = *(const f32x4*)(Wwd + (long)g * 2 * NH + i);
    *(f32x4*)(brow + i) = *(const f32x4*)(Wbd + (long)g * 2 * NH + i);
  }
  __syncthreads();
  const int lane = tid & 63, wid = tid >> 6;
  const float cw = cln_w[g], cb = cln_b[g];
  for (int b = wid; b < NB; b += 4) {
    float sw = 0.f, sb = 0.f;
#pragma unroll
    for (int c = lane * 4; c < 2 * NH; c += 256) {
      f32x4 cv = *(const f32x4*)(cond + b * 2 * NH + c);
      f32x4 wv = *(const f32x4*)(wrow + c);
      f32x4 bv = *(const f32x4*)(brow + c);
      sw += cv[0] * wv[0] + cv[1] * wv[1] + cv[2] * wv[2] + cv[3] * wv[3];
      sb += cv[0] * bv[0] + cv[1] * bv[1] + cv[2] * bv[2] + cv[3] * bv[3];
    }
    sw = wave_reduce_sum(sw);
    sb = wave_reduce_sum(sb);
    if (lane == 0) {
      wln[b * NH + g] = sw + cw;
      bln[b * NH + g] = sb + cb;
    }
  }
}

// ---- conditional LayerNorm -> normed (bf16)
__global__ __launch_bounds__(256) void ln_kernel(const float* __restrict__ x,
    const float* __restrict__ wln, const float* __restrict__ bln, short* __restrict__ normed) {
  const long row = blockIdx.x;
  const int tid = threadIdx.x;
  const long b = row >> 10;
  __shared__ float red[4];
  f32x4 v = *(const f32x4*)(x + row * NH + tid * 4);
  float mean = block_reduce_sum(v[0] + v[1] + v[2] + v[3], red) * (1.f / NH);
  float c0 = v[0] - mean, c1 = v[1] - mean, c2 = v[2] - mean, c3 = v[3] - mean;
  float var = block_reduce_sum(c0 * c0 + c1 * c1 + c2 * c2 + c3 * c3, red) * (1.f / NH);
  float rstd = rsqrtf(var + 1e-12f);
  f32x4 wv = *(const f32x4*)(wln + b * NH + tid * 4);
  f32x4 bv = *(const f32x4*)(bln + b * NH + tid * 4);
  s16x4 o = { f2bf(c0 * rstd * wv[0] + bv[0]), f2bf(c1 * rstd * wv[1] + bv[1]),
              f2bf(c2 * rstd * wv[2] + bv[2]), f2bf(c3 * rstd * wv[3] + bv[3]) };
  *(s16x4*)(normed + row * NH + tid * 4) = o;
}

// ---- fused qkv GEMM: 1536 wgs, XCD-chunked bijective swizzle (1536%8==0):
// each XCD owns 192 contiguous gids = 16 m-tiles x 12 n (n-fast) so its
// concurrent blocks share ~3 A-tiles in its private L2. z = nt>>2 is q/k/v.
// v is transposed via LDS ([256 h][264-pad t]) for coalesced vT stores.
__global__ __launch_bounds__(512, 2) void qkv_kernel(const short* __restrict__ A,
    const short* __restrict__ Wqkv,
    const float* __restrict__ bq, const float* __restrict__ bk, const float* __restrict__ bv,
    short* __restrict__ q, short* __restrict__ k, short* __restrict__ vT) {
  __shared__ short lds[67584];  // 135168 B: 128K staging, reused for vT transpose
  const int flat = blockIdx.y * 12 + blockIdx.x;     // dispatch order (x fast)
  const int gid  = (flat & 7) * 192 + (flat >> 3);   // XCD-chunked remap
  const int mt = gid / 12, nt = gid % 12;
  const short* gA = A;
  const short* gB = Wqkv;
  const long n0 = (long)nt * 256;   // row in 3072-row concat weight
  const long m0 = (long)mt * 256;
  GEMM_MAIN();
  const int z = nt >> 2;
  const long hc0 = (long)(nt & 3) * 256;  // col within H
  const float* bias = z == 0 ? bq : (z == 1 ? bk : bv);
  if (z < 2) {
    short* dst = z == 0 ? q : k;
#pragma unroll
    for (int nI = 0; nI < 4; ++nI) {
      const long col = hc0 + wn * 64 + nI * 16 + fr;
      const float bcol = bias[col];
#pragma unroll
      for (int mI = 0; mI < 8; ++mI)
#pragma unroll
        for (int r = 0; r < 4; ++r) {
          const long row = m0 + wm * 128 + mI * 16 + fq * 4 + r;
          dst[row * NH + col] = f2bf(fmaxf(acc[mI][nI][r] + bcol, 0.f));
        }
    }
  } else {
    // drain stray wrap-around stages, then reuse LDS for the transpose
    asm volatile("s_waitcnt vmcnt(0)" ::: "memory");
    __syncthreads();
#pragma unroll
    for (int nI = 0; nI < 4; ++nI) {
      const int hl = wn * 64 + nI * 16 + fr;
      const float bcol = bias[hc0 + hl];
#pragma unroll
      for (int mI = 0; mI < 8; ++mI) {
        const int tl = wm * 128 + mI * 16 + fq * 4;
        s16x4 pk = { f2bf(fmaxf(acc[mI][nI][0] + bcol, 0.f)),
                     f2bf(fmaxf(acc[mI][nI][1] + bcol, 0.f)),
                     f2bf(fmaxf(acc[mI][nI][2] + bcol, 0.f)),
                     f2bf(fmaxf(acc[mI][nI][3] + bcol, 0.f)) };
        *(s16x4*)(lds + hl * 264 + tl) = pk;
      }
    }
    __syncthreads();
    const int h = tid >> 1, half = tid & 1;
    const long bb = m0 >> 10;
    short* dst = vT + ((bb * NH) + hc0 + h) * NS + (m0 & 1023) + half * 128;
    const short* src = lds + h * 264 + half * 128;
#pragma unroll
    for (int j = 0; j < 16; ++j)
      *(s16x8*)(dst + j * 8) = *(const s16x8*)(src + j * 8);
  }
}

// ---- e[b,s,t] = q[b,s,:] . k[b,t,:] - 1e10*(1-mask[b,t])   (f32)
// 512 wgs, XCD-chunked: each XCD owns 4 whole batches (q_b/k_b L2-resident).
__global__ __launch_bounds__(512, 2) void escore_kernel(const short* __restrict__ q,
    const short* __restrict__ k, const int* __restrict__ amask, float* __restrict__ e) {
  __shared__ short lds[65536];
  const int flat = blockIdx.z * 16 + blockIdx.y * 4 + blockIdx.x;
  const int gid  = (flat & 7) * 64 + (flat >> 3);
  const int b = gid >> 4, mt = (gid >> 2) & 3, nt = gid & 3;
  const short* gA = q + (long)b * NS * NH;
  const short* gB = k + (long)b * NS * NH;
  const long m0 = (long)mt * 256;
  const long n0 = (long)nt * 256;
  GEMM_MAIN();
  float* eb = e + (long)b * NS * NS;
#pragma unroll
  for (int mI = 0; mI < 8; ++mI)
#pragma unroll
    for (int nI = 0; nI < 4; ++nI) {
      const long col = n0 + wn * 64 + nI * 16 + fr;
      const float mb = -1e10f * (1.f - (float)amask[b * NS + col]);
#pragma unroll
      for (int r = 0; r < 4; ++r) {
        const long row = m0 + wm * 128 + mI * 16 + fq * 4 + r;
        eb[row * NS + col] = acc[mI][nI][r] + mb;
      }
    }
}

// ---- row softmax: a = bf16(exp(e - max)) (unnormalized), inv_sum = 1/sum
__global__ __launch_bounds__(256) void softmax_kernel(const float* __restrict__ e,
    short* __restrict__ a, float* __restrict__ inv_sum) {
  const long row = blockIdx.x;
  const int tid = threadIdx.x;
  __shared__ float red[4];
  f32x4 v = *(const f32x4*)(e + row * NS + tid * 4);
  float m = block_reduce_max(fmaxf(fmaxf(v[0], v[1]), fmaxf(v[2], v[3])), red);
  float p0 = expf(v[0] - m), p1 = expf(v[1] - m);
  float p2 = expf(v[2] - m), p3 = expf(v[3] - m);
  float s = block_reduce_sum(p0 + p1 + p2 + p3, red);
  s16x4 o = { f2bf(p0), f2bf(p1), f2bf(p2), f2bf(p3) };
  *(s16x4*)(a + row * NS + tid * 4) = o;
  if (tid == 0) inv_sum[row] = 1.f / s;
}

// ---- hidden = (a @ v) * inv_sum + normed (f32, into d_out)
//      + fused pred partials, one slice per (n-tile, wave-column):
//      slice = nt*4 + wn, 16 slices total. XCD-chunked like escore.
__global__ __launch_bounds__(512, 2) void av_kernel(const short* __restrict__ a,
    const short* __restrict__ vT, const float* __restrict__ inv_sum,
    const short* __restrict__ normed, const float* __restrict__ Wo,
    float* __restrict__ hid, float* __restrict__ pred_part) {
  __shared__ short lds[65536];
  const int flat = blockIdx.z * 16 + blockIdx.y * 4 + blockIdx.x;
  const int gid  = (flat & 7) * 64 + (flat >> 3);
  const int b = gid >> 4, mt = (gid >> 2) & 3, nt = gid & 3;
  const short* gA = a + (long)b * NS * NS;
  const short* gB = vT + (long)b * NH * NS;
  const long m0 = (long)mt * 256;
  const long n0 = (long)nt * 256;
  GEMM_MAIN();
  float pp[8][4];
#pragma unroll
  for (int mI = 0; mI < 8; ++mI)
#pragma unroll
    for (int r = 0; r < 4; ++r) pp[mI][r] = 0.f;
#pragma unroll
  for (int nI = 0; nI < 4; ++nI) {
    const long col = n0 + wn * 64 + nI * 16 + fr;
    const float wo = Wo[col];
#pragma unroll
    for (int mI = 0; mI < 8; ++mI)
#pragma unroll
      for (int r = 0; r < 4; ++r) {
        const long row = m0 + wm * 128 + mI * 16 + fq * 4 + r;
        const long gi = ((long)b * NS + row) * NH + col;
        float hv = acc[mI][nI][r] * inv_sum[b * NS + row] + bf2f(normed[gi]);
        hid[gi] = hv;
        pp[mI][r] += hv * wo;
      }
  }
#pragma unroll
  for (int mI = 0; mI < 8; ++mI)
#pragma unroll
    for (int r = 0; r < 4; ++r) {
      float v = pp[mI][r];
      v += __shfl_xor(v, 1);
      v += __shfl_xor(v, 2);
      v += __shfl_xor(v, 4);
      v += __shfl_xor(v, 8);
      if (fr == 0)
        pred_part[((long)nt * 4 + wn) * (NB * NS) + (long)b * NS + m0 +
                  wm * 128 + mI * 16 + fq * 4 + r] = v;
    }
}

// ---- pred[row] = sum of 16 partials + bo
__global__ __launch_bounds__(256) void pred_finish_kernel(const float* __restrict__ pp,
    const float* __restrict__ bo, float* __restrict__ pred) {
  const int i = (blockIdx.x * 256 + threadIdx.x) * 4;
  const float bz = bo[0];
  f32x4 o = { bz, bz, bz, bz };
#pragma unroll
  for (int j = 0; j < 16; ++j) {
    f32x4 a = *(const f32x4*)(pp + (long)j * (NB * NS) + i);
    o[0] += a[0]; o[1] += a[1]; o[2] += a[2]; o[3] += a[3];
  }
  *(f32x4*)(pred + i) = o;
}

extern "C" void kernel_launch(void* const* d_in, const int* in_sizes, int n_in,
                              void* d_out, int out_size, void* d_ws, size_t ws_size,
                              hipStream_t stream) {
  (void)in_sizes; (void)n_in; (void)out_size; (void)ws_size;
  const int*   relation = (const int*)d_in[0];
  const float* x        = (const float*)d_in[1];
  const int*   sub_head = (const int*)d_in[2];
  const int*   sub_tail = (const int*)d_in[3];
  const int*   amask    = (const int*)d_in[4];
  const float* rel_emb  = (const float*)d_in[5];
  const float* Wrf      = (const float*)d_in[6];
  const float* brf      = (const float*)d_in[7];
  const float* cln_w    = (const float*)d_in[8];
  const float* cln_b    = (const float*)d_in[9];
  const float* Wwd      = (const float*)d_in[10];
  const float* Wbd      = (const float*)d_in[11];
  const float* Wq       = (const float*)d_in[12];
  const float* bq       = (const float*)d_in[13];
  const float* Wk       = (const float*)d_in[14];
  const float* bk       = (const float*)d_in[15];
  const float* Wv       = (const float*)d_in[16];
  const float* bv       = (const float*)d_in[17];
  const float* Wo       = (const float*)d_in[18];
  const float* bo       = (const float*)d_in[19];

  char* ws = (char*)d_ws;
  short* wqkv_bf = (short*)ws;               // 3M shorts [3072][1024]
  float* cond    = (float*)(ws + 6291456);   // [32, 2048]
  float* wln     = cond + 32 * 2048;         // [32, 1024]
  float* bln     = wln + 32 * 1024;          // [32, 1024]
  float* inv_sum = bln + 32 * 1024;          // [32768]
  short* normed  = (short*)(inv_sum + 32768);        // 33.5M bf16
  short* qb      = normed + 33554432;                // q, later reused as 'a'
  short* kb      = qb + 33554432;
  short* vT      = kb + 33554432;                    // transposed v
  float* e       = (float*)(vT + 33554432);          // 33.5M f32
  float* pred_part = e + 33554432;                   // [16][32768] f32

  float* pred = (float*)d_out;
  float* hid  = pred + 32768;

  cvtw_kernel<<<3072, 256, 0, stream>>>(Wq, Wk, Wv, wqkv_bf);
  cond_kernel<<<dim3(NB, 16), 256, 0, stream>>>(relation, x, sub_head, sub_tail,
                                                rel_emb, Wrf, brf, cond);
  wb_kernel<<<NH, 256, 0, stream>>>(cond, Wwd, Wbd, cln_w, cln_b, wln, bln);
  ln_kernel<<<NB * NS, 256, 0, stream>>>(x, wln, bln, normed);
  qkv_kernel<<<dim3(12, 128), 512, 0, stream>>>(normed, wqkv_bf,
                                                bq, bk, bv, qb, kb, vT);
  escore_kernel<<<dim3(4, 4, 32), 512, 0, stream>>>(qb, kb, amask, e);
  softmax_kernel<<<NB * NS, 256, 0, stream>>>(e, qb, inv_sum);
  av_kernel<<<dim3(4, 4, 32), 512, 0, stream>>>(qb, vT, inv_sum, normed, Wo,
                                                hid, pred_part);
  pred_finish_kernel<<<32, 256, 0, stream>>>(pred_part, bo, pred);
}